// Round 11
// baseline (1409.937 us; speedup 1.0000x reference)
//
#include <hip/hip_runtime.h>
#include <cstdint>
#include <cstddef>

#define HWPIX 16384

typedef __attribute__((ext_vector_type(8))) short bf16x8;
typedef __attribute__((ext_vector_type(4))) float f32x4;
typedef unsigned short u16;
typedef unsigned int u32;

__device__ __forceinline__ float bf2f(u16 u) {
  union { u32 i; float f; } v; v.i = ((u32)u) << 16; return v.f;
}
__device__ __forceinline__ u16 f2bf(float f) {
  union { float f; u32 i; } v; v.f = f;
  u32 x = v.i;
  return (u16)((x + 0x7fffu + ((x >> 16) & 1u)) >> 16);
}

__device__ __forceinline__ void gl_lds16(const u16* g, u16* l) {
  __builtin_amdgcn_global_load_lds((const __attribute__((address_space(1))) u32*)g,
                                   (__attribute__((address_space(3))) u32*)l,
                                   16, 0, 0);
}

// ---------------------------------------------------------------------------
// Merged weight conversion: 15 jobs in one dispatch.
// mode 0: fp32 [O][K] -> bf16 [Opad][K], rows >= O zero-filled.
// mode 1: depthwise fp32 [C][1][3][3] -> bf16 [9][C] (transposed).
// ---------------------------------------------------------------------------
struct CvtJobs {
  const float* src[15];
  u16* dst[15];
  int O[15], K[15], Opad[15], mode[15];
};

__global__ __launch_bounds__(256) void cvtall_kernel(CvtJobs jb) {
  const int j = blockIdx.y;
  const int i = blockIdx.x * 256 + threadIdx.x;
  if (jb.mode[j] == 0) {
    const int Kd8 = jb.K[j] >> 3;
    const int n8 = jb.Opad[j] * Kd8;
    if (i >= n8) return;
    const int row = i / Kd8;
    const int col = (i - row * Kd8) * 8;
    bf16x8 o;
    if (row < jb.O[j]) {
      const float* s = jb.src[j] + (size_t)row * jb.K[j] + col;
      #pragma unroll
      for (int t = 0; t < 8; ++t) o[t] = (short)f2bf(s[t]);
    } else {
      #pragma unroll
      for (int t = 0; t < 8; ++t) o[t] = 0;
    }
    *(bf16x8*)(jb.dst[j] + (size_t)i * 8) = o;
  } else {
    const int C = jb.O[j];
    const int n8 = (9 * C) >> 3;
    if (i >= n8) return;
    const int o = i * 8;
    const int t = o / C;
    const int c = o - t * C;
    bf16x8 v;
    #pragma unroll
    for (int jj = 0; jj < 8; ++jj)
      v[jj] = (short)f2bf(jb.src[j][(size_t)(c + jj) * 9 + t]);
    *(bf16x8*)(jb.dst[j] + o) = v;
  }
}

// ---------------------------------------------------------------------------
// GEMM: OutT[p][o] = epi( sum_k W[o][k] * In[p][k] ) per batch.
// BM=BN=128, BK=64; 4 waves, each 64x64 via 4x4 frags; 32 MFMA per iter.
// SOFTWARE-PIPELINED (r10 post-mortem: A-direct exposed per-iter L2 latency):
//  - B double-buffered in LDS (2x16KB); ONE barrier per K-iter.
//  - per iter: issue stage(k+1)->alt buf + prefetch A-frags(k+1)->alt regs,
//    THEN 32 MFMAs of iter k, THEN __syncthreads(). The barrier's vmcnt(0)
//    drain lands after ~155cyc of MFMA, hiding both latencies.
//  - loop unrolled x2 to ping-pong A register sets without v_mov copies.
// 1D grid, XCD-pinning swizzle (L%8 = XCD slot, o fastest; r7: FETCH 412->133MB).
// B LDS reads XOR-chunk-swizzled, conflict-free (r6: SQ_LDS_BANK_CONFLICT=0).
// epi: 0 none; 1 ddf-mul; 2 +E1 bf16T; 3 +E1 fp32 natural; 4 +E1 bf16T ->
//      fp32 natural store; 5 G=gelu(E1[ob])*(acc+E1[ofE1+ob])
// ---------------------------------------------------------------------------
__global__ __launch_bounds__(256) void gemm_k(
    const u16* __restrict__ Wt, int O, int K, int nOB,
    const u16* __restrict__ In1, int s1, int of1, int K1,
    const u16* __restrict__ In2, int s2, int of2,
    u16* __restrict__ Out, int sO,
    int epi, int halfO,
    const u16* __restrict__ E1, int sE1, int ofE1,
    const u16* __restrict__ E2, int sE2, int ofE2)
{
  const int tid  = threadIdx.x;
  const int wv   = tid >> 6;
  const int lane = tid & 63;
  const int quad = lane >> 4;
  const int l16  = lane & 15;
  const int wm   = wv >> 1;       // 0..1 (o half)
  const int wn   = wv & 1;        // 0..1 (p half)

  const int L = blockIdx.x;
  const int c = L & 7;
  const int g = L >> 3;
  const int o_blk = g % nOB;
  const int t = g / nOB;          // 0..31
  const int p_blk = ((t & 15) << 3) | c;
  const int b = t >> 4;

  const int o0 = o_blk * 128;
  const int p0 = p_blk * 128;

  __shared__ __align__(16) u16 Bs[2][128 * 64];   // 2 x 16 KB

  f32x4 acc[4][4];
  #pragma unroll
  for (int i = 0; i < 4; ++i)
    #pragma unroll
    for (int j = 0; j < 4; ++j) {
      f32x4 z = {0.f, 0.f, 0.f, 0.f};
      acc[i][j] = z;
    }

  // staging lane constants: 8-lane groups, each group covers one 128B row
  const int lrow = lane >> 3;                      // 0..7
  const int lco  = (((lane & 7) - lrow) & 7) * 8;  // swizzled k-chunk (elems)

  // A fragment pointer: lane reads W[o0+wm*64+l16 + mi*16][it*64 + w*32 + quad*8]
  const u16* wp = Wt + (size_t)(o0 + wm * 64 + l16) * K + quad * 8;
  const size_t wRow = (size_t)16 * K;   // mi stride
  const int kc1 = (K1 < K) ? K1 : K;
  const int nIter = K >> 6;

  // B stage pointers, both segments (pb2 pre-biased by -kc1; deref'd only when valid)
  const u16* pb1 = In1 + (size_t)b * HWPIX * s1 + (size_t)(p0 + wv * 32 + lrow) * s1 + of1 + lco;
  const ptrdiff_t bS1 = (ptrdiff_t)8 * s1;
  const u16* pb2 = In2 + (size_t)b * HWPIX * s2 + (size_t)(p0 + wv * 32 + lrow) * s2 + of2 + lco - kc1;
  const ptrdiff_t bS2 = (ptrdiff_t)8 * s2;

  auto stage = [&](int it, int buf) {
    const u16* p; ptrdiff_t st;
    if ((it << 6) < kc1) { p = pb1 + (it << 6); st = bS1; }
    else                 { p = pb2 + (it << 6); st = bS2; }
    #pragma unroll
    for (int i = 0; i < 4; ++i)
      gl_lds16(p + i * st, &Bs[buf][(wv * 32 + i * 8) * 64]);
  };

  bf16x8 afA[8], afB[8];
  auto preloadA = [&](int it, bf16x8* dst) {
    const u16* p = wp + (it << 6);
    #pragma unroll
    for (int w = 0; w < 2; ++w)
      #pragma unroll
      for (int mi = 0; mi < 4; ++mi)
        dst[w * 4 + mi] = *(const bf16x8*)(p + w * 32 + mi * wRow);
  };

  auto compute = [&](const bf16x8* af, int buf) {
    #pragma unroll
    for (int w = 0; w < 2; ++w) {
      const int phys = ((w * 4 + quad) + (l16 & 7)) & 7;
      bf16x8 bfr[4];
      #pragma unroll
      for (int ni = 0; ni < 4; ++ni)
        bfr[ni] = *(const bf16x8*)&Bs[buf][(wn * 64 + ni * 16 + l16) * 64 + phys * 8];
      #pragma unroll
      for (int mi = 0; mi < 4; ++mi)
        #pragma unroll
        for (int ni = 0; ni < 4; ++ni)
          acc[mi][ni] = __builtin_amdgcn_mfma_f32_16x16x32_bf16(af[w * 4 + mi], bfr[ni], acc[mi][ni], 0, 0, 0);
    }
  };

  // prologue
  stage(0, 0);
  preloadA(0, afA);
  __syncthreads();

  // pipelined main loop, unrolled x2 (even iter uses buf0/afA, odd buf1/afB)
  for (int it = 0; it < nIter; it += 2) {
    if (it + 1 < nIter) { stage(it + 1, 1); preloadA(it + 1, afB); }
    compute(afA, 0);
    __syncthreads();
    if (it + 1 >= nIter) break;
    if (it + 2 < nIter) { stage(it + 2, 0); preloadA(it + 2, afA); }
    compute(afB, 1);
    __syncthreads();
  }

  // epilogue: batch offsets
  const float* E1f = nullptr;   // epi 3: fp32 natural residual
  float* OutF = nullptr;        // epi 4: fp32 natural output
  if (epi == 3) {
    Out += (size_t)b * HWPIX * sO;
    E1f = ((const float*)E1) + (size_t)b * (size_t)O * HWPIX;
  } else if (epi == 4) {
    OutF = ((float*)Out) + (size_t)b * (size_t)O * HWPIX;
    E1 += (size_t)b * HWPIX * sE1;
  } else {
    Out += (size_t)b * HWPIX * sO;
    E1 += (size_t)b * HWPIX * sE1;
    E2 += (size_t)b * HWPIX * sE2;
  }

  #pragma unroll
  for (int mi = 0; mi < 4; ++mi)
    #pragma unroll
    for (int ni = 0; ni < 4; ++ni) {
      const int p  = p0 + wn * 64 + ni * 16 + l16;
      const int ob = o0 + wm * 64 + mi * 16 + quad * 4;
      if (ob >= O) continue;    // padded weight rows
      float v0 = acc[mi][ni][0], v1 = acc[mi][ni][1], v2 = acc[mi][ni][2], v3 = acc[mi][ni][3];
      if (epi == 1) {
        const u16* mp; int oo;
        if (ob < halfO) { mp = E1 + (size_t)p * sE1 + ofE1; oo = ob; }
        else            { mp = E2 + (size_t)p * sE2 + ofE2; oo = ob - halfO; }
        ushort4 m4 = *(const ushort4*)(mp + oo);
        v0 = (v0 + 1.f) * bf2f(m4.x);
        v1 = (v1 + 1.f) * bf2f(m4.y);
        v2 = (v2 + 1.f) * bf2f(m4.z);
        v3 = (v3 + 1.f) * bf2f(m4.w);
      } else if (epi == 2) {
        ushort4 r4 = *(const ushort4*)(E1 + (size_t)p * sE1 + ofE1 + ob);
        v0 += bf2f(r4.x); v1 += bf2f(r4.y); v2 += bf2f(r4.z); v3 += bf2f(r4.w);
      } else if (epi == 3) {
        v0 += E1f[(size_t)(ob + 0) * HWPIX + p];
        v1 += E1f[(size_t)(ob + 1) * HWPIX + p];
        v2 += E1f[(size_t)(ob + 2) * HWPIX + p];
        v3 += E1f[(size_t)(ob + 3) * HWPIX + p];
      } else if (epi == 4) {
        ushort4 r4 = *(const ushort4*)(E1 + (size_t)p * sE1 + ob);
        v0 += bf2f(r4.x); v1 += bf2f(r4.y); v2 += bf2f(r4.z); v3 += bf2f(r4.w);
        if (!__builtin_isfinite(v0)) v0 = 10000.f;
        if (!__builtin_isfinite(v1)) v1 = 10000.f;
        if (!__builtin_isfinite(v2)) v2 = 10000.f;
        if (!__builtin_isfinite(v3)) v3 = 10000.f;
        OutF[(size_t)(ob + 0) * HWPIX + p] = v0;
        OutF[(size_t)(ob + 1) * HWPIX + p] = v1;
        OutF[(size_t)(ob + 2) * HWPIX + p] = v2;
        OutF[(size_t)(ob + 3) * HWPIX + p] = v3;
        continue;
      } else if (epi == 5) {
        ushort4 r4 = *(const ushort4*)(E1 + (size_t)p * sE1 + ofE1 + ob);
        ushort4 x4 = *(const ushort4*)(E1 + (size_t)p * sE1 + ob);
        float x;
        x = bf2f(x4.x); v0 = (v0 + bf2f(r4.x)) * 0.5f * x * (1.f + erff(x * 0.70710678118f));
        x = bf2f(x4.y); v1 = (v1 + bf2f(r4.y)) * 0.5f * x * (1.f + erff(x * 0.70710678118f));
        x = bf2f(x4.z); v2 = (v2 + bf2f(r4.z)) * 0.5f * x * (1.f + erff(x * 0.70710678118f));
        x = bf2f(x4.w); v3 = (v3 + bf2f(r4.w)) * 0.5f * x * (1.f + erff(x * 0.70710678118f));
      }
      ushort4 s4;
      s4.x = f2bf(v0); s4.y = f2bf(v1); s4.z = f2bf(v2); s4.w = f2bf(v3);
      *(ushort4*)(Out + (size_t)p * sO + ob) = s4;
    }
}

// ---------------------------------------------------------------------------
// LayerNorm over C=192. natural=1: inF fp32 [b][192][HW]; natural=0: inB bf16
// [b][HW][192]. Output always bf16 transposed [b][HW][192].
// ---------------------------------------------------------------------------
__global__ __launch_bounds__(128) void ln_kernel(
    const float* __restrict__ inF, const u16* __restrict__ inB, int natural,
    const float* __restrict__ gw, const float* __restrict__ gb,
    u16* __restrict__ out)
{
  __shared__ u16 tile[128 * 194];   // +2 pad -> 2-way max bank aliasing (free)
  __shared__ float smu[128], srs[128];
  const int tid = threadIdx.x;
  const int p0  = blockIdx.x * 128;
  const int b   = blockIdx.y;
  const size_t CHW = (size_t)192 * HWPIX;
  out += (size_t)b * CHW;
  if (natural) {
    inF += (size_t)b * CHW;
    float s = 0.f, s2 = 0.f;
    for (int c = 0; c < 192; ++c) {
      float v = inF[(size_t)c * HWPIX + p0 + tid];
      s += v; s2 += v * v;
      tile[tid * 194 + c] = f2bf(v);
    }
    float m = s * (1.f / 192.f);
    smu[tid] = m;
    srs[tid] = rsqrtf(fmaxf(s2 * (1.f / 192.f) - m * m, 0.f) + 1e-5f);
  } else {
    inB += (size_t)b * CHW;
    for (int g = tid; g < 128 * 192; g += 128) {
      int p = g / 192, c = g - p * 192;
      tile[p * 194 + c] = inB[(size_t)(p0 + p) * 192 + c];
    }
    __syncthreads();
    float s = 0.f, s2 = 0.f;
    for (int c = 0; c < 192; ++c) {
      float v = bf2f(tile[tid * 194 + c]);
      s += v; s2 += v * v;
    }
    float m = s * (1.f / 192.f);
    smu[tid] = m;
    srs[tid] = rsqrtf(fmaxf(s2 * (1.f / 192.f) - m * m, 0.f) + 1e-5f);
  }
  __syncthreads();
  for (int g = tid; g < 128 * 192; g += 128) {
    int p = g / 192, c = g - p * 192;
    float v = bf2f(tile[p * 194 + c]);
    float y = (v - smu[p]) * srs[p] * gw[c] + gb[c];
    out[(size_t)(p0 + p) * 192 + c] = f2bf(y);
  }
}

// ---------------------------------------------------------------------------
// Depthwise 3x3 SAME on transposed layout [b][HW][C].
// 8 channels x 4 consecutive w-pixels per thread; weights pre-transposed [9][C].
// ---------------------------------------------------------------------------
__global__ __launch_bounds__(256) void dwconv_kernel(
    const u16* __restrict__ in, const u16* __restrict__ wtT,
    u16* __restrict__ out, int C, int cg8)
{
  int idx = blockIdx.x * 256 + threadIdx.x;
  int cg   = idx % cg8;
  int rest = idx / cg8;
  int c  = cg << 3;
  int wg = rest & 31;
  int hb = rest >> 5;            // b*128 + h
  int h  = hb & 127;
  int w0 = wg << 2;

  float acc[4][8];
  #pragma unroll
  for (int px = 0; px < 4; ++px)
    #pragma unroll
    for (int j = 0; j < 8; ++j) acc[px][j] = 0.f;

  #pragma unroll
  for (int r = 0; r < 3; ++r) {
    int hh = h + r - 1;
    if (hh < 0 || hh > 127) continue;
    const u16* rowp = in + (size_t)(hb + r - 1) * 128 * C + c;
    bf16x8 v[6];
    #pragma unroll
    for (int t = 0; t < 6; ++t) {
      int ww = w0 + t - 1;
      if (ww < 0 || ww > 127) {
        #pragma unroll
        for (int j = 0; j < 8; ++j) v[t][j] = 0;
      } else {
        v[t] = *(const bf16x8*)(rowp + (size_t)ww * C);
      }
    }
    bf16x8 wv[3];
    #pragma unroll
    for (int kx = 0; kx < 3; ++kx)
      wv[kx] = *(const bf16x8*)(wtT + (size_t)(r * 3 + kx) * C + c);
    #pragma unroll
    for (int kx = 0; kx < 3; ++kx) {
      float wf[8];
      #pragma unroll
      for (int j = 0; j < 8; ++j) wf[j] = bf2f((u16)wv[kx][j]);
      #pragma unroll
      for (int px = 0; px < 4; ++px)
        #pragma unroll
        for (int j = 0; j < 8; ++j)
          acc[px][j] += bf2f((u16)v[px + kx][j]) * wf[j];
    }
  }

  #pragma unroll
  for (int px = 0; px < 4; ++px) {
    bf16x8 ov;
    #pragma unroll
    for (int j = 0; j < 8; ++j) ov[j] = (short)f2bf(acc[px][j]);
    *(bf16x8*)(out + (size_t)(hb * 128 + w0 + px) * C + c) = ov;
  }
}

// Sum of squares over pixels for q (ch 0..191) and k (ch 192..383) of QKVd.
__global__ __launch_bounds__(256) void norms_kernel(
    const u16* __restrict__ qkv, float* __restrict__ nrm)
{
  __shared__ float lacc[384];
  const int b = blockIdx.y, p0 = blockIdx.x * 128;
  for (int i = threadIdx.x; i < 384; i += 256) lacc[i] = 0.f;
  __syncthreads();
  const u16* base = qkv + (size_t)b * HWPIX * 576;
  for (int g = threadIdx.x; g < 128 * 48; g += 256) {
    int p = g / 48, cg = g - p * 48;
    bf16x8 v = *(const bf16x8*)(base + (size_t)(p0 + p) * 576 + cg * 8);
    #pragma unroll
    for (int j = 0; j < 8; ++j) {
      float x = bf2f((u16)v[j]);
      atomicAdd(&lacc[cg * 8 + j], x * x);
    }
  }
  __syncthreads();
  for (int i = threadIdx.x; i < 384; i += 256)
    atomicAdd(&nrm[b * 384 + i], lacc[i]);
}

// raw[b][h][c][d] += sum_p Q[p][h*32+c] * K[p][h*32+d]  (unnormalized dots)
__global__ __launch_bounds__(256) void qk_kernel(
    const u16* __restrict__ qkv, float* __restrict__ raw)
{
  __shared__ __align__(16) u16 Qt[64 * 32];
  __shared__ __align__(16) u16 Kt[64 * 32];
  const int b = blockIdx.z, h = blockIdx.y;
  const int tid = threadIdx.x;
  const u16* base = qkv + (size_t)b * HWPIX * 576;
  const int c = tid & 31, dg = tid >> 5;    // dg 0..7
  const int row = tid >> 2, colg = tid & 3;
  float a0 = 0.f, a1 = 0.f, a2 = 0.f, a3 = 0.f;
  const int pstart = blockIdx.x * 512;
  for (int p0 = pstart; p0 < pstart + 512; p0 += 64) {
    __syncthreads();
    const u16* qs = base + (size_t)(p0 + row) * 576 + h * 32 + colg * 8;
    *(bf16x8*)(Qt + row * 32 + colg * 8) = *(const bf16x8*)qs;
    *(bf16x8*)(Kt + row * 32 + colg * 8) = *(const bf16x8*)(qs + 192);
    __syncthreads();
    #pragma unroll 4
    for (int pp = 0; pp < 64; ++pp) {
      float qv = bf2f(Qt[pp * 32 + c]);
      a0 += qv * bf2f(Kt[pp * 32 + dg * 4 + 0]);
      a1 += qv * bf2f(Kt[pp * 32 + dg * 4 + 1]);
      a2 += qv * bf2f(Kt[pp * 32 + dg * 4 + 2]);
      a3 += qv * bf2f(Kt[pp * 32 + dg * 4 + 3]);
    }
  }
  float* dst = raw + (((size_t)(b * 6 + h) * 32 + c) * 32) + dg * 4;
  atomicAdd(dst + 0, a0);
  atomicAdd(dst + 1, a1);
  atomicAdd(dst + 2, a2);
  atomicAdd(dst + 3, a3);
}

// logits = raw * (1/max(|q|,eps)) * (1/max(|k|,eps)) * temp[h]; softmax over d(32)
__global__ __launch_bounds__(256) void softmax_kernel(
    float* __restrict__ raw, const float* __restrict__ nrm, const float* __restrict__ temp)
{
  int gid = blockIdx.x * 256 + threadIdx.x;   // 12288 total
  int d = gid & 31;
  int rowid = gid >> 5;
  int c = rowid & 31;
  int bh = rowid >> 5;
  int h = bh % 6, b = bh / 6;
  float sq = 1.f / fmaxf(sqrtf(nrm[b * 384 + h * 32 + c]), 1e-12f);
  float sk = 1.f / fmaxf(sqrtf(nrm[b * 384 + 192 + h * 32 + d]), 1e-12f);
  float logit = raw[gid] * sq * sk * temp[h];
  float m = logit;
  #pragma unroll
  for (int off = 16; off >= 1; off >>= 1)
    m = fmaxf(m, __shfl_xor(m, off, 32));
  float e = expf(logit - m);
  float s = e;
  #pragma unroll
  for (int off = 16; off >= 1; off >>= 1)
    s += __shfl_xor(s, off, 32);
  raw[gid] = e / s;
}

// out[p][h*32+cc] = sum_d attn[b][h][cc][d] * V[p][384+h*32+d]
__global__ __launch_bounds__(256) void attnout_kernel(
    const u16* __restrict__ qkv, const float* __restrict__ attn, u16* __restrict__ out)
{
  __shared__ float A[1024];
  const int b = blockIdx.z, h = blockIdx.y;
  const int p0 = blockIdx.x * 256;
  const float* am = attn + ((size_t)(b * 6 + h) * 32) * 32;
  for (int i = threadIdx.x; i < 1024; i += 256) A[i] = am[i];
  __syncthreads();
  const size_t pg = (size_t)b * HWPIX + p0 + threadIdx.x;
  const u16* vrow = qkv + pg * 576 + 384 + h * 32;
  float v[32];
  #pragma unroll
  for (int t = 0; t < 4; ++t) {
    bf16x8 vv = *(const bf16x8*)(vrow + t * 8);
    #pragma unroll
    for (int j = 0; j < 8; ++j) v[t * 8 + j] = bf2f((u16)vv[j]);
  }
  u16* orow = out + pg * 192 + h * 32;
  #pragma unroll
  for (int t = 0; t < 4; ++t) {
    bf16x8 ov;
    #pragma unroll
    for (int j = 0; j < 8; ++j) {
      const float* ar = &A[(t * 8 + j) * 32];
      float s = 0.f;
      #pragma unroll
      for (int d4 = 0; d4 < 8; ++d4) {
        f32x4 a4 = *(const f32x4*)(ar + d4 * 4);
        s += a4.x * v[d4 * 4 + 0] + a4.y * v[d4 * 4 + 1]
           + a4.z * v[d4 * 4 + 2] + a4.w * v[d4 * 4 + 3];
      }
      ov[j] = (short)f2bf(s);
    }
    *(bf16x8*)(orow + t * 8) = ov;
  }
}

__global__ void zero_kernel(float* p, int n) {
  int i = blockIdx.x * 256 + threadIdx.x;
  if (i < n) p[i] = 0.f;
}

// ---------------------------------------------------------------------------
extern "C" void kernel_launch(void* const* d_in, const int* in_sizes, int n_in,
                              void* d_out, int out_size, void* d_ws, size_t ws_size,
                              hipStream_t stream)
{
  (void)in_sizes; (void)n_in; (void)out_size; (void)ws_size;
  typedef const float* fp;
  fp x_in    = (fp)d_in[0];
  fp f_in    = (fp)d_in[1];
  fp nf_w    = (fp)d_in[2];
  fp nf_b    = (fp)d_in[3];
  fp n1_w    = (fp)d_in[4];
  fp n1_b    = (fp)d_in[5];
  fp n2_w    = (fp)d_in[6];
  fp n2_b    = (fp)d_in[7];
  fp a_cc_f  = (fp)d_in[8];
  fp a_fu_f  = (fp)d_in[9];
  fp a_mk_f  = (fp)d_in[10];
  fp a_qkv_f = (fp)d_in[11];
  fp a_dw_f  = (fp)d_in[12];
  fp a_temp  = (fp)d_in[13];
  fp a_pr_f  = (fp)d_in[14];
  fp f_pm_f  = (fp)d_in[15];
  fp f_pi_f  = (fp)d_in[16];
  fp f_dw_f  = (fp)d_in[17];
  fp f_cc_f  = (fp)d_in[18];
  fp f_fu_f  = (fp)d_in[19];
  fp f_mk_f  = (fp)d_in[20];
  fp f_po_f  = (fp)d_in[21];

  char* wsb = (char*)d_ws;
  const size_t U = 65536;   // bytes per channel-slab: 2 batches * 16384 px * 2B
  u16* Y     = (u16*)(wsb + (size_t)0    * U);  // [0,192)   residual, whole session
  u16* X1    = (u16*)(wsb + (size_t)192  * U);  // [192,384) until a_fu
  u16* MT    = (u16*)(wsb + (size_t)384  * U);  // [384,576) until a_cc
  float* nrm = (float*)(wsb + (size_t)576 * U); // slab 576 (52 KB) until attnout
  float* raw = nrm + 768;
  u16* QKV   = (u16*)(wsb + (size_t)640  * U);  // [640,1216) qkv gemm -> dwconv_a
  u16* OUT12 = (u16*)(wsb + (size_t)1344 * U);  // [1344,1728) a_cc -> a_fu
  u16* QKVd  = (u16*)(wsb + (size_t)1344 * U);  // [1344,1920) dwconv_a -> attnout
  u16* DW    = (u16*)(wsb + (size_t)1344 * U);  // [1344,2496) dwconv_f -> f_fu epi
  u16* FM    = (u16*)(wsb + (size_t)1920 * U);  // [1920,2496) f_pm -> f_mk
  u16* F     = (u16*)(wsb + (size_t)2496 * U);  // [2496,2688) ln_f -> a_mk
  u16* XD    = (u16*)(wsb + (size_t)2496 * U);  // a_fu -> qkv gemm
  u16* X2    = (u16*)(wsb + (size_t)2496 * U);  // ln2 -> f_pi
  u16* MT2   = (u16*)(wsb + (size_t)2496 * U);  // [2496,3072) f_mk -> f_cc epi
  u16* G     = (u16*)(wsb + (size_t)2496 * U);  // [2496,3072) f_fu epi5 -> final
  u16* AO    = (u16*)(wsb + (size_t)192  * U);  // attnout -> a_proj (X1 dead)
  u16* XIN   = (u16*)(wsb + (size_t)192  * U);  // [192,1344) f_pi -> dwconv_f
  u16* O12B  = (u16*)(wsb + (size_t)192  * U);  // f_cc -> f_fu
  // bf16 weight pool at [3072,...): rows padded to mult of 128
  u16* Wb    = (u16*)(wsb + (size_t)3072 * U);
  u16* a_cc_w  = Wb + 0;        // 384x384
  u16* a_fu_w  = Wb + 147456;   // 256x384 (O=192)
  u16* a_mk_w  = Wb + 245760;   // 256x192 (O=192)
  u16* a_qkv_w = Wb + 294912;   // 640x192 (O=576)
  u16* a_dw_w  = Wb + 417792;   // [9][576]
  u16* a_pr_w  = Wb + 422976;   // 256x192 (O=192)
  u16* f_pm_w  = Wb + 472128;   // 640x192 (O=576)
  u16* f_pi_w  = Wb + 595008;   // 1152x192
  u16* f_dw_w  = Wb + 816192;   // [9][1152]
  u16* f_cc_w  = Wb + 826560;   // 1152x1152
  u16* f_fu_w  = Wb + 2153664;  // 640x1152 (O=576)
  u16* f_mk_w  = Wb + 2890944;  // 640x576 (O=576)
  u16* f_po_w  = Wb + 3259584;  // 256x576 (O=192)

  CvtJobs jb;
  const float* srcs[15] = {a_cc_f, a_fu_f, a_mk_f, a_qkv_f, a_pr_f, f_pm_f,
                           f_pi_f, f_cc_f, f_fu_f, f_mk_f, f_po_f, a_dw_f, f_dw_f,
                           nullptr, nullptr};
  u16* dsts[15] = {a_cc_w, a_fu_w, a_mk_w, a_qkv_w, a_pr_w, f_pm_w,
                   f_pi_w, f_cc_w, f_fu_w, f_mk_w, f_po_w, a_dw_w, f_dw_w,
                   nullptr, nullptr};
  int Os[15]    = {384, 192, 192, 576, 192, 576, 1152, 1152, 576, 576, 192, 576, 1152, 0, 0};
  int Ks[15]    = {384, 384, 192, 192, 192, 192, 192, 1152, 1152, 576, 576, 0, 0, 8, 8};
  int Opads[15] = {384, 256, 256, 640, 256, 640, 1152, 1152, 640, 640, 256, 0, 0, 0, 0};
  int modes[15] = {0, 0, 0, 0, 0, 0, 0, 0, 0, 0, 0, 1, 1, 1, 1};
  for (int i = 0; i < 15; ++i) {
    jb.src[i] = srcs[i] ? srcs[i] : a_dw_f;
    jb.dst[i] = dsts[i] ? dsts[i] : a_dw_w;
    jb.O[i] = srcs[i] ? Os[i] : 8;
    jb.K[i] = Ks[i]; jb.Opad[i] = Opads[i]; jb.mode[i] = modes[i];
  }
  cvtall_kernel<<<dim3(648, 15), 256, 0, stream>>>(jb);

  dim3 lngrid(128, 2);
  zero_kernel<<<51, 256, 0, stream>>>(nrm, 13056);
  ln_kernel<<<lngrid, 128, 0, stream>>>(f_in, nullptr, 1, nf_w, nf_b, F);
  ln_kernel<<<lngrid, 128, 0, stream>>>(x_in, nullptr, 1, n1_w, n1_b, X1);

#define GEMM(W_, O_, OP_, K_, I1, S1, OF1, K1_, I2, S2, OF2, OUT_, SO_, EPI_, HALF_, E1_, SE1_, OFE1_, E2_, SE2_, OFE2_) \
  gemm_k<<<dim3(((OP_) / 128) * 256), 256, 0, stream>>>(W_, O_, K_, (OP_) / 128, I1, S1, OF1, K1_, I2, S2, OF2, OUT_, SO_, EPI_, HALF_, E1_, SE1_, OFE1_, E2_, SE2_, OFE2_)

  // FM = projmask @ F
  GEMM(f_pm_w, 576, 640, 192, F, 192, 0, 192, F, 192, 0, FM, 576, 0, 0, F, 192, 0, F, 192, 0);
  // MT = a_mask @ F
  GEMM(a_mk_w, 192, 256, 192, F, 192, 0, 192, F, 192, 0, MT, 192, 0, 0, F, 192, 0, F, 192, 0);
  // OUT12 = (a_concat @ [X1;MT] + 1) * [X1;MT]
  GEMM(a_cc_w, 384, 384, 384, X1, 192, 0, 192, MT, 192, 0, OUT12, 384, 1, 192, X1, 192, 0, MT, 192, 0);
  // XD = a_fusion @ OUT12 + X1
  GEMM(a_fu_w, 192, 256, 384, OUT12, 384, 0, 384, OUT12, 384, 0, XD, 192, 2, 0, X1, 192, 0, X1, 192, 0);
  // QKV = a_qkv @ XD
  GEMM(a_qkv_w, 576, 640, 192, XD, 192, 0, 192, XD, 192, 0, QKV, 576, 0, 0, XD, 192, 0, XD, 192, 0);
  dwconv_kernel<<<2304, 256, 0, stream>>>(QKV, a_dw_w, QKVd, 576, 72);
  norms_kernel<<<dim3(128, 2), 256, 0, stream>>>(QKVd, nrm);
  qk_kernel<<<dim3(32, 6, 2), 256, 0, stream>>>(QKVd, raw);
  softmax_kernel<<<48, 256, 0, stream>>>(raw, nrm, a_temp);
  attnout_kernel<<<dim3(64, 6, 2), 256, 0, stream>>>(QKVd, raw, AO);
  // Y = a_proj @ AO + x (natural fp32 residual)
  GEMM(a_pr_w, 192, 256, 192, AO, 192, 0, 192, AO, 192, 0, Y, 192, 3, 0, (const u16*)x_in, 0, 0, (const u16*)x_in, 0, 0);
  ln_kernel<<<lngrid, 128, 0, stream>>>(nullptr, Y, 0, n2_w, n2_b, X2);
  // XIN = projin @ X2
  GEMM(f_pi_w, 1152, 1152, 192, X2, 192, 0, 192, X2, 192, 0, XIN, 1152, 0, 0, X2, 192, 0, X2, 192, 0);
  // MT2 = f_mask @ FM   (after f_pi; before dwconv_f kills FM)
  GEMM(f_mk_w, 576, 640, 576, FM, 576, 0, 576, FM, 576, 0, MT2, 576, 0, 0, FM, 576, 0, FM, 576, 0);
  dwconv_kernel<<<4608, 256, 0, stream>>>(XIN, f_dw_w, DW, 1152, 144);
  // O12B = (f_concat @ [x2;MT2] + 1) * [x2;MT2]   (x2 = DW cols 576..1151)
  GEMM(f_cc_w, 1152, 1152, 1152, DW, 1152, 576, 576, MT2, 576, 0, O12B, 1152, 1, 576, DW, 1152, 576, MT2, 576, 0);
  // G = gelu(x1) * (f_fusion @ O12B + x2)   (fused epi 5)
  GEMM(f_fu_w, 576, 640, 1152, O12B, 1152, 0, 1152, O12B, 1152, 0, G, 576, 5, 0, DW, 1152, 576, DW, 1152, 576);
  // out = f_projout @ G + Y, stored natural fp32 [b][192][H][W]
  GEMM(f_po_w, 192, 256, 576, G, 576, 0, 576, G, 576, 0, (u16*)d_out, 192, 4, 0, Y, 192, 0, Y, 192, 0);
#undef GEMM
}

// Round 12
// 916.167 us; speedup vs baseline: 1.5390x; 1.5390x over previous
//
#include <hip/hip_runtime.h>
#include <cstdint>
#include <cstddef>

#define HWPIX 16384

typedef __attribute__((ext_vector_type(8))) short bf16x8;
typedef __attribute__((ext_vector_type(4))) float f32x4;
typedef unsigned short u16;
typedef unsigned int u32;

__device__ __forceinline__ float bf2f(u16 u) {
  union { u32 i; float f; } v; v.i = ((u32)u) << 16; return v.f;
}
__device__ __forceinline__ u16 f2bf(float f) {
  union { float f; u32 i; } v; v.f = f;
  u32 x = v.i;
  return (u16)((x + 0x7fffu + ((x >> 16) & 1u)) >> 16);
}

__device__ __forceinline__ void gl_lds16(const u16* g, u16* l) {
  __builtin_amdgcn_global_load_lds((const __attribute__((address_space(1))) u32*)g,
                                   (__attribute__((address_space(3))) u32*)l,
                                   16, 0, 0);
}

// fast gelu (tanh form, max err ~3e-4 vs exact): x * sigmoid(1.5957691*(x+0.044715x^3))
__device__ __forceinline__ float gelu_fast(float x) {
  float x2 = x * x;
  float tt = 1.5957691216f * x * (1.f + 0.044715f * x2);
  return x / (1.f + __expf(-tt));
}

// ---------------------------------------------------------------------------
// Merged weight conversion: 15 jobs in one dispatch.
// mode 0: fp32 [O][K] -> bf16 [Opad][K], rows >= O zero-filled.
// mode 1: depthwise fp32 [C][1][3][3] -> bf16 [9][C] (transposed).
// ---------------------------------------------------------------------------
struct CvtJobs {
  const float* src[15];
  u16* dst[15];
  int O[15], K[15], Opad[15], mode[15];
};

__global__ __launch_bounds__(256) void cvtall_kernel(CvtJobs jb) {
  const int j = blockIdx.y;
  const int i = blockIdx.x * 256 + threadIdx.x;
  if (jb.mode[j] == 0) {
    const int Kd8 = jb.K[j] >> 3;
    const int n8 = jb.Opad[j] * Kd8;
    if (i >= n8) return;
    const int row = i / Kd8;
    const int col = (i - row * Kd8) * 8;
    bf16x8 o;
    if (row < jb.O[j]) {
      const float* s = jb.src[j] + (size_t)row * jb.K[j] + col;
      #pragma unroll
      for (int t = 0; t < 8; ++t) o[t] = (short)f2bf(s[t]);
    } else {
      #pragma unroll
      for (int t = 0; t < 8; ++t) o[t] = 0;
    }
    *(bf16x8*)(jb.dst[j] + (size_t)i * 8) = o;
  } else {
    const int C = jb.O[j];
    const int n8 = (9 * C) >> 3;
    if (i >= n8) return;
    const int o = i * 8;
    const int t = o / C;
    const int c = o - t * C;
    bf16x8 v;
    #pragma unroll
    for (int jj = 0; jj < 8; ++jj)
      v[jj] = (short)f2bf(jb.src[j][(size_t)(c + jj) * 9 + t]);
    *(bf16x8*)(jb.dst[j] + o) = v;
  }
}

// ---------------------------------------------------------------------------
// GEMM (r7 structure — best measured, 958us total; r10/r11 pipelining attempts
// both regressed and are abandoned per m99-m141 guidance):
// BM=BN=128, BK=64; 4 waves, each 64x64 via 4x4 frags; 32 MFMA per barrier.
// A+B staged via global_load_lds w=16 with XOR chunk swizzle (conflict-free,
// r6: SQ_LDS_BANK_CONFLICT=0). 1D grid, XCD-pinning swizzle (L%8 = XCD slot,
// o fastest; r7: FETCH 412->133MB). K-loop split In1/In2 with strength-reduced
// staging pointers (r8: VALUBusy 36->lower via no addr remat).
// epi: 0 none; 1 ddf-mul; 2 +E1 bf16T; 3 +E1 fp32 natural; 4 +E1 bf16T ->
//      fp32 natural store; 5 G=gelu(E1[ob])*(acc+E1[ofE1+ob]) (fast gelu)
// ---------------------------------------------------------------------------
__global__ __launch_bounds__(256) void gemm_k(
    const u16* __restrict__ Wt, int O, int K, int nOB,
    const u16* __restrict__ In1, int s1, int of1, int K1,
    const u16* __restrict__ In2, int s2, int of2,
    u16* __restrict__ Out, int sO,
    int epi, int halfO,
    const u16* __restrict__ E1, int sE1, int ofE1,
    const u16* __restrict__ E2, int sE2, int ofE2)
{
  const int tid  = threadIdx.x;
  const int wv   = tid >> 6;
  const int lane = tid & 63;
  const int quad = lane >> 4;
  const int l16  = lane & 15;
  const int wm   = wv >> 1;       // 0..1 (o half)
  const int wn   = wv & 1;        // 0..1 (p half)

  const int L = blockIdx.x;
  const int c = L & 7;
  const int g = L >> 3;
  const int o_blk = g % nOB;
  const int t = g / nOB;          // 0..31
  const int p_blk = ((t & 15) << 3) | c;
  const int b = t >> 4;

  const int o0 = o_blk * 128;
  const int p0 = p_blk * 128;

  __shared__ __align__(16) u16 As[128 * 64];   // 16 KB
  __shared__ __align__(16) u16 Bs[128 * 64];   // 16 KB

  f32x4 acc[4][4];
  #pragma unroll
  for (int i = 0; i < 4; ++i)
    #pragma unroll
    for (int j = 0; j < 4; ++j) {
      f32x4 z = {0.f, 0.f, 0.f, 0.f};
      acc[i][j] = z;
    }

  // staging lane constants: 8-lane groups, each group covers one 128B row
  const int lrow = lane >> 3;                      // 0..7
  const int lco  = (((lane & 7) - lrow) & 7) * 8;  // swizzled k-chunk (elems)

  auto compute = [&]() {
    #pragma unroll
    for (int w = 0; w < 2; ++w) {
      const int phys = ((w * 4 + quad) + (l16 & 7)) & 7;
      bf16x8 af[4], bfr[4];
      #pragma unroll
      for (int mi = 0; mi < 4; ++mi)
        af[mi]  = *(const bf16x8*)&As[(wm * 64 + mi * 16 + l16) * 64 + phys * 8];
      #pragma unroll
      for (int ni = 0; ni < 4; ++ni)
        bfr[ni] = *(const bf16x8*)&Bs[(wn * 64 + ni * 16 + l16) * 64 + phys * 8];
      #pragma unroll
      for (int mi = 0; mi < 4; ++mi)
        #pragma unroll
        for (int ni = 0; ni < 4; ++ni)
          acc[mi][ni] = __builtin_amdgcn_mfma_f32_16x16x32_bf16(af[mi], bfr[ni], acc[mi][ni], 0, 0, 0);
    }
  };

  const u16* pa = Wt + (size_t)(o0 + wv * 32 + lrow) * K + lco;
  const size_t aS = (size_t)8 * K;
  const int kc1 = (K1 < K) ? K1 : K;

  {
    const u16* pb = In1 + (size_t)b * HWPIX * s1 + (size_t)(p0 + wv * 32 + lrow) * s1 + of1 + lco;
    const size_t bS = (size_t)8 * s1;
    for (int kk = 0; kk < kc1; kk += 64) {
      #pragma unroll
      for (int i = 0; i < 4; ++i) {
        gl_lds16(pa + i * aS, &As[(wv * 32 + i * 8) * 64]);
        gl_lds16(pb + i * bS, &Bs[(wv * 32 + i * 8) * 64]);
      }
      pa += 64; pb += 64;
      __syncthreads();
      compute();
      __syncthreads();
    }
  }
  if (K > kc1) {
    const u16* pb = In2 + (size_t)b * HWPIX * s2 + (size_t)(p0 + wv * 32 + lrow) * s2 + of2 + lco;
    const size_t bS = (size_t)8 * s2;
    for (int kk = kc1; kk < K; kk += 64) {
      #pragma unroll
      for (int i = 0; i < 4; ++i) {
        gl_lds16(pa + i * aS, &As[(wv * 32 + i * 8) * 64]);
        gl_lds16(pb + i * bS, &Bs[(wv * 32 + i * 8) * 64]);
      }
      pa += 64; pb += 64;
      __syncthreads();
      compute();
      __syncthreads();
    }
  }

  // epilogue: batch offsets
  const float* E1f = nullptr;   // epi 3: fp32 natural residual
  float* OutF = nullptr;        // epi 4: fp32 natural output
  if (epi == 3) {
    Out += (size_t)b * HWPIX * sO;
    E1f = ((const float*)E1) + (size_t)b * (size_t)O * HWPIX;
  } else if (epi == 4) {
    OutF = ((float*)Out) + (size_t)b * (size_t)O * HWPIX;
    E1 += (size_t)b * HWPIX * sE1;
  } else {
    Out += (size_t)b * HWPIX * sO;
    E1 += (size_t)b * HWPIX * sE1;
    E2 += (size_t)b * HWPIX * sE2;
  }

  #pragma unroll
  for (int mi = 0; mi < 4; ++mi)
    #pragma unroll
    for (int ni = 0; ni < 4; ++ni) {
      const int p  = p0 + wn * 64 + ni * 16 + l16;
      const int ob = o0 + wm * 64 + mi * 16 + quad * 4;
      if (ob >= O) continue;    // padded weight rows
      float v0 = acc[mi][ni][0], v1 = acc[mi][ni][1], v2 = acc[mi][ni][2], v3 = acc[mi][ni][3];
      if (epi == 1) {
        const u16* mp; int oo;
        if (ob < halfO) { mp = E1 + (size_t)p * sE1 + ofE1; oo = ob; }
        else            { mp = E2 + (size_t)p * sE2 + ofE2; oo = ob - halfO; }
        ushort4 m4 = *(const ushort4*)(mp + oo);
        v0 = (v0 + 1.f) * bf2f(m4.x);
        v1 = (v1 + 1.f) * bf2f(m4.y);
        v2 = (v2 + 1.f) * bf2f(m4.z);
        v3 = (v3 + 1.f) * bf2f(m4.w);
      } else if (epi == 2) {
        ushort4 r4 = *(const ushort4*)(E1 + (size_t)p * sE1 + ofE1 + ob);
        v0 += bf2f(r4.x); v1 += bf2f(r4.y); v2 += bf2f(r4.z); v3 += bf2f(r4.w);
      } else if (epi == 3) {
        v0 += E1f[(size_t)(ob + 0) * HWPIX + p];
        v1 += E1f[(size_t)(ob + 1) * HWPIX + p];
        v2 += E1f[(size_t)(ob + 2) * HWPIX + p];
        v3 += E1f[(size_t)(ob + 3) * HWPIX + p];
      } else if (epi == 4) {
        ushort4 r4 = *(const ushort4*)(E1 + (size_t)p * sE1 + ob);
        v0 += bf2f(r4.x); v1 += bf2f(r4.y); v2 += bf2f(r4.z); v3 += bf2f(r4.w);
        if (!__builtin_isfinite(v0)) v0 = 10000.f;
        if (!__builtin_isfinite(v1)) v1 = 10000.f;
        if (!__builtin_isfinite(v2)) v2 = 10000.f;
        if (!__builtin_isfinite(v3)) v3 = 10000.f;
        OutF[(size_t)(ob + 0) * HWPIX + p] = v0;
        OutF[(size_t)(ob + 1) * HWPIX + p] = v1;
        OutF[(size_t)(ob + 2) * HWPIX + p] = v2;
        OutF[(size_t)(ob + 3) * HWPIX + p] = v3;
        continue;
      } else if (epi == 5) {
        ushort4 r4 = *(const ushort4*)(E1 + (size_t)p * sE1 + ofE1 + ob);
        ushort4 x4 = *(const ushort4*)(E1 + (size_t)p * sE1 + ob);
        v0 = (v0 + bf2f(r4.x)) * gelu_fast(bf2f(x4.x));
        v1 = (v1 + bf2f(r4.y)) * gelu_fast(bf2f(x4.y));
        v2 = (v2 + bf2f(r4.z)) * gelu_fast(bf2f(x4.z));
        v3 = (v3 + bf2f(r4.w)) * gelu_fast(bf2f(x4.w));
      }
      ushort4 s4;
      s4.x = f2bf(v0); s4.y = f2bf(v1); s4.z = f2bf(v2); s4.w = f2bf(v3);
      *(ushort4*)(Out + (size_t)p * sO + ob) = s4;
    }
}

// ---------------------------------------------------------------------------
// LayerNorm over C=192. natural=1: inF fp32 [b][192][HW]; natural=0: inB bf16
// [b][HW][192]. Output always bf16 transposed [b][HW][192].
// ---------------------------------------------------------------------------
__global__ __launch_bounds__(128) void ln_kernel(
    const float* __restrict__ inF, const u16* __restrict__ inB, int natural,
    const float* __restrict__ gw, const float* __restrict__ gb,
    u16* __restrict__ out)
{
  __shared__ u16 tile[128 * 194];   // +2 pad -> 2-way max bank aliasing (free)
  __shared__ float smu[128], srs[128];
  const int tid = threadIdx.x;
  const int p0  = blockIdx.x * 128;
  const int b   = blockIdx.y;
  const size_t CHW = (size_t)192 * HWPIX;
  out += (size_t)b * CHW;
  if (natural) {
    inF += (size_t)b * CHW;
    float s = 0.f, s2 = 0.f;
    for (int c = 0; c < 192; ++c) {
      float v = inF[(size_t)c * HWPIX + p0 + tid];
      s += v; s2 += v * v;
      tile[tid * 194 + c] = f2bf(v);
    }
    float m = s * (1.f / 192.f);
    smu[tid] = m;
    srs[tid] = rsqrtf(fmaxf(s2 * (1.f / 192.f) - m * m, 0.f) + 1e-5f);
  } else {
    inB += (size_t)b * CHW;
    for (int g = tid; g < 128 * 192; g += 128) {
      int p = g / 192, c = g - p * 192;
      tile[p * 194 + c] = inB[(size_t)(p0 + p) * 192 + c];
    }
    __syncthreads();
    float s = 0.f, s2 = 0.f;
    for (int c = 0; c < 192; ++c) {
      float v = bf2f(tile[tid * 194 + c]);
      s += v; s2 += v * v;
    }
    float m = s * (1.f / 192.f);
    smu[tid] = m;
    srs[tid] = rsqrtf(fmaxf(s2 * (1.f / 192.f) - m * m, 0.f) + 1e-5f);
  }
  __syncthreads();
  for (int g = tid; g < 128 * 192; g += 128) {
    int p = g / 192, c = g - p * 192;
    float v = bf2f(tile[p * 194 + c]);
    float y = (v - smu[p]) * srs[p] * gw[c] + gb[c];
    out[(size_t)(p0 + p) * 192 + c] = f2bf(y);
  }
}

// ---------------------------------------------------------------------------
// Depthwise 3x3 SAME on transposed layout [b][HW][C].
// 8 channels x 4 consecutive w-pixels per thread; weights pre-transposed [9][C].
// ---------------------------------------------------------------------------
__global__ __launch_bounds__(256) void dwconv_kernel(
    const u16* __restrict__ in, const u16* __restrict__ wtT,
    u16* __restrict__ out, int C, int cg8)
{
  int idx = blockIdx.x * 256 + threadIdx.x;
  int cg   = idx % cg8;
  int rest = idx / cg8;
  int c  = cg << 3;
  int wg = rest & 31;
  int hb = rest >> 5;            // b*128 + h
  int h  = hb & 127;
  int w0 = wg << 2;

  float acc[4][8];
  #pragma unroll
  for (int px = 0; px < 4; ++px)
    #pragma unroll
    for (int j = 0; j < 8; ++j) acc[px][j] = 0.f;

  #pragma unroll
  for (int r = 0; r < 3; ++r) {
    int hh = h + r - 1;
    if (hh < 0 || hh > 127) continue;
    const u16* rowp = in + (size_t)(hb + r - 1) * 128 * C + c;
    bf16x8 v[6];
    #pragma unroll
    for (int t = 0; t < 6; ++t) {
      int ww = w0 + t - 1;
      if (ww < 0 || ww > 127) {
        #pragma unroll
        for (int j = 0; j < 8; ++j) v[t][j] = 0;
      } else {
        v[t] = *(const bf16x8*)(rowp + (size_t)ww * C);
      }
    }
    bf16x8 wv[3];
    #pragma unroll
    for (int kx = 0; kx < 3; ++kx)
      wv[kx] = *(const bf16x8*)(wtT + (size_t)(r * 3 + kx) * C + c);
    #pragma unroll
    for (int kx = 0; kx < 3; ++kx) {
      float wf[8];
      #pragma unroll
      for (int j = 0; j < 8; ++j) wf[j] = bf2f((u16)wv[kx][j]);
      #pragma unroll
      for (int px = 0; px < 4; ++px)
        #pragma unroll
        for (int j = 0; j < 8; ++j)
          acc[px][j] += bf2f((u16)v[px + kx][j]) * wf[j];
    }
  }

  #pragma unroll
  for (int px = 0; px < 4; ++px) {
    bf16x8 ov;
    #pragma unroll
    for (int j = 0; j < 8; ++j) ov[j] = (short)f2bf(acc[px][j]);
    *(bf16x8*)(out + (size_t)(hb * 128 + w0 + px) * C + c) = ov;
  }
}

// Sum of squares over pixels for q (ch 0..191) and k (ch 192..383) of QKVd.
__global__ __launch_bounds__(256) void norms_kernel(
    const u16* __restrict__ qkv, float* __restrict__ nrm)
{
  __shared__ float lacc[384];
  const int b = blockIdx.y, p0 = blockIdx.x * 128;
  for (int i = threadIdx.x; i < 384; i += 256) lacc[i] = 0.f;
  __syncthreads();
  const u16* base = qkv + (size_t)b * HWPIX * 576;
  for (int g = threadIdx.x; g < 128 * 48; g += 256) {
    int p = g / 48, cg = g - p * 48;
    bf16x8 v = *(const bf16x8*)(base + (size_t)(p0 + p) * 576 + cg * 8);
    #pragma unroll
    for (int j = 0; j < 8; ++j) {
      float x = bf2f((u16)v[j]);
      atomicAdd(&lacc[cg * 8 + j], x * x);
    }
  }
  __syncthreads();
  for (int i = threadIdx.x; i < 384; i += 256)
    atomicAdd(&nrm[b * 384 + i], lacc[i]);
}

// raw[b][h][c][d] += sum_p Q[p][h*32+c] * K[p][h*32+d]  (unnormalized dots)
__global__ __launch_bounds__(256) void qk_kernel(
    const u16* __restrict__ qkv, float* __restrict__ raw)
{
  __shared__ __align__(16) u16 Qt[64 * 32];
  __shared__ __align__(16) u16 Kt[64 * 32];
  const int b = blockIdx.z, h = blockIdx.y;
  const int tid = threadIdx.x;
  const u16* base = qkv + (size_t)b * HWPIX * 576;
  const int c = tid & 31, dg = tid >> 5;    // dg 0..7
  const int row = tid >> 2, colg = tid & 3;
  float a0 = 0.f, a1 = 0.f, a2 = 0.f, a3 = 0.f;
  const int pstart = blockIdx.x * 512;
  for (int p0 = pstart; p0 < pstart + 512; p0 += 64) {
    __syncthreads();
    const u16* qs = base + (size_t)(p0 + row) * 576 + h * 32 + colg * 8;
    *(bf16x8*)(Qt + row * 32 + colg * 8) = *(const bf16x8*)qs;
    *(bf16x8*)(Kt + row * 32 + colg * 8) = *(const bf16x8*)(qs + 192);
    __syncthreads();
    #pragma unroll 4
    for (int pp = 0; pp < 64; ++pp) {
      float qv = bf2f(Qt[pp * 32 + c]);
      a0 += qv * bf2f(Kt[pp * 32 + dg * 4 + 0]);
      a1 += qv * bf2f(Kt[pp * 32 + dg * 4 + 1]);
      a2 += qv * bf2f(Kt[pp * 32 + dg * 4 + 2]);
      a3 += qv * bf2f(Kt[pp * 32 + dg * 4 + 3]);
    }
  }
  float* dst = raw + (((size_t)(b * 6 + h) * 32 + c) * 32) + dg * 4;
  atomicAdd(dst + 0, a0);
  atomicAdd(dst + 1, a1);
  atomicAdd(dst + 2, a2);
  atomicAdd(dst + 3, a3);
}

// logits = raw * (1/max(|q|,eps)) * (1/max(|k|,eps)) * temp[h]; softmax over d(32)
__global__ __launch_bounds__(256) void softmax_kernel(
    float* __restrict__ raw, const float* __restrict__ nrm, const float* __restrict__ temp)
{
  int gid = blockIdx.x * 256 + threadIdx.x;   // 12288 total
  int d = gid & 31;
  int rowid = gid >> 5;
  int c = rowid & 31;
  int bh = rowid >> 5;
  int h = bh % 6, b = bh / 6;
  float sq = 1.f / fmaxf(sqrtf(nrm[b * 384 + h * 32 + c]), 1e-12f);
  float sk = 1.f / fmaxf(sqrtf(nrm[b * 384 + 192 + h * 32 + d]), 1e-12f);
  float logit = raw[gid] * sq * sk * temp[h];
  float m = logit;
  #pragma unroll
  for (int off = 16; off >= 1; off >>= 1)
    m = fmaxf(m, __shfl_xor(m, off, 32));
  float e = expf(logit - m);
  float s = e;
  #pragma unroll
  for (int off = 16; off >= 1; off >>= 1)
    s += __shfl_xor(s, off, 32);
  raw[gid] = e / s;
}

// out[p][h*32+cc] = sum_d attn[b][h][cc][d] * V[p][384+h*32+d]
__global__ __launch_bounds__(256) void attnout_kernel(
    const u16* __restrict__ qkv, const float* __restrict__ attn, u16* __restrict__ out)
{
  __shared__ float A[1024];
  const int b = blockIdx.z, h = blockIdx.y;
  const int p0 = blockIdx.x * 256;
  const float* am = attn + ((size_t)(b * 6 + h) * 32) * 32;
  for (int i = threadIdx.x; i < 1024; i += 256) A[i] = am[i];
  __syncthreads();
  const size_t pg = (size_t)b * HWPIX + p0 + threadIdx.x;
  const u16* vrow = qkv + pg * 576 + 384 + h * 32;
  float v[32];
  #pragma unroll
  for (int t = 0; t < 4; ++t) {
    bf16x8 vv = *(const bf16x8*)(vrow + t * 8);
    #pragma unroll
    for (int j = 0; j < 8; ++j) v[t * 8 + j] = bf2f((u16)vv[j]);
  }
  u16* orow = out + pg * 192 + h * 32;
  #pragma unroll
  for (int t = 0; t < 4; ++t) {
    bf16x8 ov;
    #pragma unroll
    for (int j = 0; j < 8; ++j) {
      const float* ar = &A[(t * 8 + j) * 32];
      float s = 0.f;
      #pragma unroll
      for (int d4 = 0; d4 < 8; ++d4) {
        f32x4 a4 = *(const f32x4*)(ar + d4 * 4);
        s += a4.x * v[d4 * 4 + 0] + a4.y * v[d4 * 4 + 1]
           + a4.z * v[d4 * 4 + 2] + a4.w * v[d4 * 4 + 3];
      }
      ov[j] = (short)f2bf(s);
    }
    *(bf16x8*)(orow + t * 8) = ov;
  }
}

__global__ void zero_kernel(float* p, int n) {
  int i = blockIdx.x * 256 + threadIdx.x;
  if (i < n) p[i] = 0.f;
}

// ---------------------------------------------------------------------------
extern "C" void kernel_launch(void* const* d_in, const int* in_sizes, int n_in,
                              void* d_out, int out_size, void* d_ws, size_t ws_size,
                              hipStream_t stream)
{
  (void)in_sizes; (void)n_in; (void)out_size; (void)ws_size;
  typedef const float* fp;
  fp x_in    = (fp)d_in[0];
  fp f_in    = (fp)d_in[1];
  fp nf_w    = (fp)d_in[2];
  fp nf_b    = (fp)d_in[3];
  fp n1_w    = (fp)d_in[4];
  fp n1_b    = (fp)d_in[5];
  fp n2_w    = (fp)d_in[6];
  fp n2_b    = (fp)d_in[7];
  fp a_cc_f  = (fp)d_in[8];
  fp a_fu_f  = (fp)d_in[9];
  fp a_mk_f  = (fp)d_in[10];
  fp a_qkv_f = (fp)d_in[11];
  fp a_dw_f  = (fp)d_in[12];
  fp a_temp  = (fp)d_in[13];
  fp a_pr_f  = (fp)d_in[14];
  fp f_pm_f  = (fp)d_in[15];
  fp f_pi_f  = (fp)d_in[16];
  fp f_dw_f  = (fp)d_in[17];
  fp f_cc_f  = (fp)d_in[18];
  fp f_fu_f  = (fp)d_in[19];
  fp f_mk_f  = (fp)d_in[20];
  fp f_po_f  = (fp)d_in[21];

  char* wsb = (char*)d_ws;
  const size_t U = 65536;   // bytes per channel-slab: 2 batches * 16384 px * 2B
  u16* Y     = (u16*)(wsb + (size_t)0    * U);  // [0,192)   residual, whole session
  u16* X1    = (u16*)(wsb + (size_t)192  * U);  // [192,384) until a_fu
  u16* MT    = (u16*)(wsb + (size_t)384  * U);  // [384,576) until a_cc
  float* nrm = (float*)(wsb + (size_t)576 * U); // slab 576 (52 KB) until attnout
  float* raw = nrm + 768;
  u16* QKV   = (u16*)(wsb + (size_t)640  * U);  // [640,1216) qkv gemm -> dwconv_a
  u16* OUT12 = (u16*)(wsb + (size_t)1344 * U);  // [1344,1728) a_cc -> a_fu
  u16* QKVd  = (u16*)(wsb + (size_t)1344 * U);  // [1344,1920) dwconv_a -> attnout
  u16* DW    = (u16*)(wsb + (size_t)1344 * U);  // [1344,2496) dwconv_f -> f_fu epi
  u16* FM    = (u16*)(wsb + (size_t)1920 * U);  // [1920,2496) f_pm -> f_mk
  u16* F     = (u16*)(wsb + (size_t)2496 * U);  // [2496,2688) ln_f -> a_mk
  u16* XD    = (u16*)(wsb + (size_t)2496 * U);  // a_fu -> qkv gemm
  u16* X2    = (u16*)(wsb + (size_t)2496 * U);  // ln2 -> f_pi
  u16* MT2   = (u16*)(wsb + (size_t)2496 * U);  // [2496,3072) f_mk -> f_cc epi
  u16* G     = (u16*)(wsb + (size_t)2496 * U);  // [2496,3072) f_fu epi5 -> final
  u16* AO    = (u16*)(wsb + (size_t)192  * U);  // attnout -> a_proj (X1 dead)
  u16* XIN   = (u16*)(wsb + (size_t)192  * U);  // [192,1344) f_pi -> dwconv_f
  u16* O12B  = (u16*)(wsb + (size_t)192  * U);  // f_cc -> f_fu
  // bf16 weight pool at [3072,...): rows padded to mult of 128
  u16* Wb    = (u16*)(wsb + (size_t)3072 * U);
  u16* a_cc_w  = Wb + 0;        // 384x384
  u16* a_fu_w  = Wb + 147456;   // 256x384 (O=192)
  u16* a_mk_w  = Wb + 245760;   // 256x192 (O=192)
  u16* a_qkv_w = Wb + 294912;   // 640x192 (O=576)
  u16* a_dw_w  = Wb + 417792;   // [9][576]
  u16* a_pr_w  = Wb + 422976;   // 256x192 (O=192)
  u16* f_pm_w  = Wb + 472128;   // 640x192 (O=576)
  u16* f_pi_w  = Wb + 595008;   // 1152x192
  u16* f_dw_w  = Wb + 816192;   // [9][1152]
  u16* f_cc_w  = Wb + 826560;   // 1152x1152
  u16* f_fu_w  = Wb + 2153664;  // 640x1152 (O=576)
  u16* f_mk_w  = Wb + 2890944;  // 640x576 (O=576)
  u16* f_po_w  = Wb + 3259584;  // 256x576 (O=192)

  CvtJobs jb;
  const float* srcs[15] = {a_cc_f, a_fu_f, a_mk_f, a_qkv_f, a_pr_f, f_pm_f,
                           f_pi_f, f_cc_f, f_fu_f, f_mk_f, f_po_f, a_dw_f, f_dw_f,
                           nullptr, nullptr};
  u16* dsts[15] = {a_cc_w, a_fu_w, a_mk_w, a_qkv_w, a_pr_w, f_pm_w,
                   f_pi_w, f_cc_w, f_fu_w, f_mk_w, f_po_w, a_dw_w, f_dw_w,
                   nullptr, nullptr};
  int Os[15]    = {384, 192, 192, 576, 192, 576, 1152, 1152, 576, 576, 192, 576, 1152, 0, 0};
  int Ks[15]    = {384, 384, 192, 192, 192, 192, 192, 1152, 1152, 576, 576, 0, 0, 8, 8};
  int Opads[15] = {384, 256, 256, 640, 256, 640, 1152, 1152, 640, 640, 256, 0, 0, 0, 0};
  int modes[15] = {0, 0, 0, 0, 0, 0, 0, 0, 0, 0, 0, 1, 1, 1, 1};
  for (int i = 0; i < 15; ++i) {
    jb.src[i] = srcs[i] ? srcs[i] : a_dw_f;
    jb.dst[i] = dsts[i] ? dsts[i] : a_dw_w;
    jb.O[i] = srcs[i] ? Os[i] : 8;
    jb.K[i] = Ks[i]; jb.Opad[i] = Opads[i]; jb.mode[i] = modes[i];
  }
  cvtall_kernel<<<dim3(648, 15), 256, 0, stream>>>(jb);

  dim3 lngrid(128, 2);
  zero_kernel<<<51, 256, 0, stream>>>(nrm, 13056);
  ln_kernel<<<lngrid, 128, 0, stream>>>(f_in, nullptr, 1, nf_w, nf_b, F);
  ln_kernel<<<lngrid, 128, 0, stream>>>(x_in, nullptr, 1, n1_w, n1_b, X1);

#define GEMM(W_, O_, OP_, K_, I1, S1, OF1, K1_, I2, S2, OF2, OUT_, SO_, EPI_, HALF_, E1_, SE1_, OFE1_, E2_, SE2_, OFE2_) \
  gemm_k<<<dim3(((OP_) / 128) * 256), 256, 0, stream>>>(W_, O_, K_, (OP_) / 128, I1, S1, OF1, K1_, I2, S2, OF2, OUT_, SO_, EPI_, HALF_, E1_, SE1_, OFE1_, E2_, SE2_, OFE2_)

  // FM = projmask @ F
  GEMM(f_pm_w, 576, 640, 192, F, 192, 0, 192, F, 192, 0, FM, 576, 0, 0, F, 192, 0, F, 192, 0);
  // MT = a_mask @ F
  GEMM(a_mk_w, 192, 256, 192, F, 192, 0, 192, F, 192, 0, MT, 192, 0, 0, F, 192, 0, F, 192, 0);
  // OUT12 = (a_concat @ [X1;MT] + 1) * [X1;MT]
  GEMM(a_cc_w, 384, 384, 384, X1, 192, 0, 192, MT, 192, 0, OUT12, 384, 1, 192, X1, 192, 0, MT, 192, 0);
  // XD = a_fusion @ OUT12 + X1
  GEMM(a_fu_w, 192, 256, 384, OUT12, 384, 0, 384, OUT12, 384, 0, XD, 192, 2, 0, X1, 192, 0, X1, 192, 0);
  // QKV = a_qkv @ XD
  GEMM(a_qkv_w, 576, 640, 192, XD, 192, 0, 192, XD, 192, 0, QKV, 576, 0, 0, XD, 192, 0, XD, 192, 0);
  dwconv_kernel<<<2304, 256, 0, stream>>>(QKV, a_dw_w, QKVd, 576, 72);
  norms_kernel<<<dim3(128, 2), 256, 0, stream>>>(QKVd, nrm);
  qk_kernel<<<dim3(32, 6, 2), 256, 0, stream>>>(QKVd, raw);
  softmax_kernel<<<48, 256, 0, stream>>>(raw, nrm, a_temp);
  attnout_kernel<<<dim3(64, 6, 2), 256, 0, stream>>>(QKVd, raw, AO);
  // Y = a_proj @ AO + x (natural fp32 residual)
  GEMM(a_pr_w, 192, 256, 192, AO, 192, 0, 192, AO, 192, 0, Y, 192, 3, 0, (const u16*)x_in, 0, 0, (const u16*)x_in, 0, 0);
  ln_kernel<<<lngrid, 128, 0, stream>>>(nullptr, Y, 0, n2_w, n2_b, X2);
  // XIN = projin @ X2
  GEMM(f_pi_w, 1152, 1152, 192, X2, 192, 0, 192, X2, 192, 0, XIN, 1152, 0, 0, X2, 192, 0, X2, 192, 0);
  // MT2 = f_mask @ FM   (after f_pi; before dwconv_f kills FM)
  GEMM(f_mk_w, 576, 640, 576, FM, 576, 0, 576, FM, 576, 0, MT2, 576, 0, 0, FM, 576, 0, FM, 576, 0);
  dwconv_kernel<<<4608, 256, 0, stream>>>(XIN, f_dw_w, DW, 1152, 144);
  // O12B = (f_concat @ [x2;MT2] + 1) * [x2;MT2]   (x2 = DW cols 576..1151)
  GEMM(f_cc_w, 1152, 1152, 1152, DW, 1152, 576, 576, MT2, 576, 0, O12B, 1152, 1, 576, DW, 1152, 576, MT2, 576, 0);
  // G = gelu(x1) * (f_fusion @ O12B + x2)   (fused epi 5, fast gelu)
  GEMM(f_fu_w, 576, 640, 1152, O12B, 1152, 0, 1152, O12B, 1152, 0, G, 576, 5, 0, DW, 1152, 576, DW, 1152, 576);
  // out = f_projout @ G + Y, stored natural fp32 [b][192][H][W]
  GEMM(f_po_w, 192, 256, 576, G, 576, 0, 576, G, 576, 0, (u16*)d_out, 192, 4, 0, Y, 192, 0, Y, 192, 0);
#undef GEMM
}

// Round 13
// 821.981 us; speedup vs baseline: 1.7153x; 1.1146x over previous
//
#include <hip/hip_runtime.h>
#include <cstdint>
#include <cstddef>

#define HWPIX 16384

typedef __attribute__((ext_vector_type(8))) short bf16x8;
typedef __attribute__((ext_vector_type(4))) float f32x4;
typedef unsigned short u16;
typedef unsigned int u32;

__device__ __forceinline__ float bf2f(u16 u) {
  union { u32 i; float f; } v; v.i = ((u32)u) << 16; return v.f;
}
__device__ __forceinline__ u16 f2bf(float f) {
  union { float f; u32 i; } v; v.f = f;
  u32 x = v.i;
  return (u16)((x + 0x7fffu + ((x >> 16) & 1u)) >> 16);
}

__device__ __forceinline__ void gl_lds16(const u16* g, u16* l) {
  __builtin_amdgcn_global_load_lds((const __attribute__((address_space(1))) u32*)g,
                                   (__attribute__((address_space(3))) u32*)l,
                                   16, 0, 0);
}

// fast gelu (tanh form, max err ~3e-4 vs exact): x * sigmoid(1.5957691*(x+0.044715x^3))
__device__ __forceinline__ float gelu_fast(float x) {
  float x2 = x * x;
  float tt = 1.5957691216f * x * (1.f + 0.044715f * x2);
  return x / (1.f + __expf(-tt));
}

// ---------------------------------------------------------------------------
// Merged weight conversion: 15 jobs in one dispatch.
// mode 0: fp32 [O][K] -> bf16 [Opad][K], rows >= O zero-filled.
// mode 1: depthwise fp32 [C][1][3][3] -> bf16 [9][C] (transposed).
// ---------------------------------------------------------------------------
struct CvtJobs {
  const float* src[15];
  u16* dst[15];
  int O[15], K[15], Opad[15], mode[15];
};

__global__ __launch_bounds__(256) void cvtall_kernel(CvtJobs jb) {
  const int j = blockIdx.y;
  const int i = blockIdx.x * 256 + threadIdx.x;
  if (jb.mode[j] == 0) {
    const int Kd8 = jb.K[j] >> 3;
    const int n8 = jb.Opad[j] * Kd8;
    if (i >= n8) return;
    const int row = i / Kd8;
    const int col = (i - row * Kd8) * 8;
    bf16x8 o;
    if (row < jb.O[j]) {
      const float* s = jb.src[j] + (size_t)row * jb.K[j] + col;
      #pragma unroll
      for (int t = 0; t < 8; ++t) o[t] = (short)f2bf(s[t]);
    } else {
      #pragma unroll
      for (int t = 0; t < 8; ++t) o[t] = 0;
    }
    *(bf16x8*)(jb.dst[j] + (size_t)i * 8) = o;
  } else {
    const int C = jb.O[j];
    const int n8 = (9 * C) >> 3;
    if (i >= n8) return;
    const int o = i * 8;
    const int t = o / C;
    const int c = o - t * C;
    bf16x8 v;
    #pragma unroll
    for (int jj = 0; jj < 8; ++jj)
      v[jj] = (short)f2bf(jb.src[j][(size_t)(c + jj) * 9 + t]);
    *(bf16x8*)(jb.dst[j] + o) = v;
  }
}

// ---------------------------------------------------------------------------
// GEMM (r7 structure, best measured; r12: 916us total, top gemm 156us @23% MFMA).
// BM=BN=128, BK=64; 4 waves, each 64x64 via 4x4 frags; 32 MFMA per barrier.
// A+B staged via global_load_lds w=16 with XOR chunk swizzle (conflict-free,
// r6). 1D grid, XCD-pinning swizzle (r7: FETCH 412->133MB). K-loop split.
// __launch_bounds__(256,3): r12 showed VGPR 112 + 64 AGPR (unified file) =
// ~176 regs -> 2 waves/SIMD -> 20% occupancy; cap at 170 for 3 waves/SIMD.
// epi: 0 none; 1 ddf-mul; 2 +E1 bf16T; 3 +E1 fp32 natural; 4 +E1 bf16T ->
//      fp32 natural store; 5 G=gelu(E1[ob])*(acc+E1[ofE1+ob]) (fast gelu)
// ---------------------------------------------------------------------------
__global__ __launch_bounds__(256, 3) void gemm_k(
    const u16* __restrict__ Wt, int O, int K, int nOB,
    const u16* __restrict__ In1, int s1, int of1, int K1,
    const u16* __restrict__ In2, int s2, int of2,
    u16* __restrict__ Out, int sO,
    int epi, int halfO,
    const u16* __restrict__ E1, int sE1, int ofE1,
    const u16* __restrict__ E2, int sE2, int ofE2)
{
  const int tid  = threadIdx.x;
  const int wv   = tid >> 6;
  const int lane = tid & 63;
  const int quad = lane >> 4;
  const int l16  = lane & 15;
  const int wm   = wv >> 1;       // 0..1 (o half)
  const int wn   = wv & 1;        // 0..1 (p half)

  const int L = blockIdx.x;
  const int c = L & 7;
  const int g = L >> 3;
  const int o_blk = g % nOB;
  const int t = g / nOB;          // 0..31
  const int p_blk = ((t & 15) << 3) | c;
  const int b = t >> 4;

  const int o0 = o_blk * 128;
  const int p0 = p_blk * 128;

  __shared__ __align__(16) u16 As[128 * 64];   // 16 KB
  __shared__ __align__(16) u16 Bs[128 * 64];   // 16 KB

  f32x4 acc[4][4];
  #pragma unroll
  for (int i = 0; i < 4; ++i)
    #pragma unroll
    for (int j = 0; j < 4; ++j) {
      f32x4 z = {0.f, 0.f, 0.f, 0.f};
      acc[i][j] = z;
    }

  // staging lane constants: 8-lane groups, each group covers one 128B row
  const int lrow = lane >> 3;                      // 0..7
  const int lco  = (((lane & 7) - lrow) & 7) * 8;  // swizzled k-chunk (elems)

  auto compute = [&]() {
    #pragma unroll
    for (int w = 0; w < 2; ++w) {
      const int phys = ((w * 4 + quad) + (l16 & 7)) & 7;
      bf16x8 af[4], bfr[4];
      #pragma unroll
      for (int mi = 0; mi < 4; ++mi)
        af[mi]  = *(const bf16x8*)&As[(wm * 64 + mi * 16 + l16) * 64 + phys * 8];
      #pragma unroll
      for (int ni = 0; ni < 4; ++ni)
        bfr[ni] = *(const bf16x8*)&Bs[(wn * 64 + ni * 16 + l16) * 64 + phys * 8];
      #pragma unroll
      for (int mi = 0; mi < 4; ++mi)
        #pragma unroll
        for (int ni = 0; ni < 4; ++ni)
          acc[mi][ni] = __builtin_amdgcn_mfma_f32_16x16x32_bf16(af[mi], bfr[ni], acc[mi][ni], 0, 0, 0);
    }
  };

  const u16* pa = Wt + (size_t)(o0 + wv * 32 + lrow) * K + lco;
  const size_t aS = (size_t)8 * K;
  const int kc1 = (K1 < K) ? K1 : K;

  {
    const u16* pb = In1 + (size_t)b * HWPIX * s1 + (size_t)(p0 + wv * 32 + lrow) * s1 + of1 + lco;
    const size_t bS = (size_t)8 * s1;
    for (int kk = 0; kk < kc1; kk += 64) {
      #pragma unroll
      for (int i = 0; i < 4; ++i) {
        gl_lds16(pa + i * aS, &As[(wv * 32 + i * 8) * 64]);
        gl_lds16(pb + i * bS, &Bs[(wv * 32 + i * 8) * 64]);
      }
      pa += 64; pb += 64;
      __syncthreads();
      compute();
      __syncthreads();
    }
  }
  if (K > kc1) {
    const u16* pb = In2 + (size_t)b * HWPIX * s2 + (size_t)(p0 + wv * 32 + lrow) * s2 + of2 + lco;
    const size_t bS = (size_t)8 * s2;
    for (int kk = kc1; kk < K; kk += 64) {
      #pragma unroll
      for (int i = 0; i < 4; ++i) {
        gl_lds16(pa + i * aS, &As[(wv * 32 + i * 8) * 64]);
        gl_lds16(pb + i * bS, &Bs[(wv * 32 + i * 8) * 64]);
      }
      pa += 64; pb += 64;
      __syncthreads();
      compute();
      __syncthreads();
    }
  }

  // epilogue: batch offsets
  const float* E1f = nullptr;   // epi 3: fp32 natural residual
  float* OutF = nullptr;        // epi 4: fp32 natural output
  if (epi == 3) {
    Out += (size_t)b * HWPIX * sO;
    E1f = ((const float*)E1) + (size_t)b * (size_t)O * HWPIX;
  } else if (epi == 4) {
    OutF = ((float*)Out) + (size_t)b * (size_t)O * HWPIX;
    E1 += (size_t)b * HWPIX * sE1;
  } else {
    Out += (size_t)b * HWPIX * sO;
    E1 += (size_t)b * HWPIX * sE1;
    E2 += (size_t)b * HWPIX * sE2;
  }

  #pragma unroll
  for (int mi = 0; mi < 4; ++mi)
    #pragma unroll
    for (int ni = 0; ni < 4; ++ni) {
      const int p  = p0 + wn * 64 + ni * 16 + l16;
      const int ob = o0 + wm * 64 + mi * 16 + quad * 4;
      if (ob >= O) continue;    // padded weight rows
      float v0 = acc[mi][ni][0], v1 = acc[mi][ni][1], v2 = acc[mi][ni][2], v3 = acc[mi][ni][3];
      if (epi == 1) {
        const u16* mp; int oo;
        if (ob < halfO) { mp = E1 + (size_t)p * sE1 + ofE1; oo = ob; }
        else            { mp = E2 + (size_t)p * sE2 + ofE2; oo = ob - halfO; }
        ushort4 m4 = *(const ushort4*)(mp + oo);
        v0 = (v0 + 1.f) * bf2f(m4.x);
        v1 = (v1 + 1.f) * bf2f(m4.y);
        v2 = (v2 + 1.f) * bf2f(m4.z);
        v3 = (v3 + 1.f) * bf2f(m4.w);
      } else if (epi == 2) {
        ushort4 r4 = *(const ushort4*)(E1 + (size_t)p * sE1 + ofE1 + ob);
        v0 += bf2f(r4.x); v1 += bf2f(r4.y); v2 += bf2f(r4.z); v3 += bf2f(r4.w);
      } else if (epi == 3) {
        v0 += E1f[(size_t)(ob + 0) * HWPIX + p];
        v1 += E1f[(size_t)(ob + 1) * HWPIX + p];
        v2 += E1f[(size_t)(ob + 2) * HWPIX + p];
        v3 += E1f[(size_t)(ob + 3) * HWPIX + p];
      } else if (epi == 4) {
        ushort4 r4 = *(const ushort4*)(E1 + (size_t)p * sE1 + ob);
        v0 += bf2f(r4.x); v1 += bf2f(r4.y); v2 += bf2f(r4.z); v3 += bf2f(r4.w);
        if (!__builtin_isfinite(v0)) v0 = 10000.f;
        if (!__builtin_isfinite(v1)) v1 = 10000.f;
        if (!__builtin_isfinite(v2)) v2 = 10000.f;
        if (!__builtin_isfinite(v3)) v3 = 10000.f;
        OutF[(size_t)(ob + 0) * HWPIX + p] = v0;
        OutF[(size_t)(ob + 1) * HWPIX + p] = v1;
        OutF[(size_t)(ob + 2) * HWPIX + p] = v2;
        OutF[(size_t)(ob + 3) * HWPIX + p] = v3;
        continue;
      } else if (epi == 5) {
        ushort4 r4 = *(const ushort4*)(E1 + (size_t)p * sE1 + ofE1 + ob);
        ushort4 x4 = *(const ushort4*)(E1 + (size_t)p * sE1 + ob);
        v0 = (v0 + bf2f(r4.x)) * gelu_fast(bf2f(x4.x));
        v1 = (v1 + bf2f(r4.y)) * gelu_fast(bf2f(x4.y));
        v2 = (v2 + bf2f(r4.z)) * gelu_fast(bf2f(x4.z));
        v3 = (v3 + bf2f(r4.w)) * gelu_fast(bf2f(x4.w));
      }
      ushort4 s4;
      s4.x = f2bf(v0); s4.y = f2bf(v1); s4.z = f2bf(v2); s4.w = f2bf(v3);
      *(ushort4*)(Out + (size_t)p * sO + ob) = s4;
    }
}

// ---------------------------------------------------------------------------
// LayerNorm over C=192. natural=1: inF fp32 [b][192][HW]; natural=0: inB bf16
// [b][HW][192]. Output always bf16 transposed [b][HW][192].
// ---------------------------------------------------------------------------
__global__ __launch_bounds__(128) void ln_kernel(
    const float* __restrict__ inF, const u16* __restrict__ inB, int natural,
    const float* __restrict__ gw, const float* __restrict__ gb,
    u16* __restrict__ out)
{
  __shared__ u16 tile[128 * 194];   // +2 pad -> 2-way max bank aliasing (free)
  __shared__ float smu[128], srs[128];
  const int tid = threadIdx.x;
  const int p0  = blockIdx.x * 128;
  const int b   = blockIdx.y;
  const size_t CHW = (size_t)192 * HWPIX;
  out += (size_t)b * CHW;
  if (natural) {
    inF += (size_t)b * CHW;
    float s = 0.f, s2 = 0.f;
    for (int c = 0; c < 192; ++c) {
      float v = inF[(size_t)c * HWPIX + p0 + tid];
      s += v; s2 += v * v;
      tile[tid * 194 + c] = f2bf(v);
    }
    float m = s * (1.f / 192.f);
    smu[tid] = m;
    srs[tid] = rsqrtf(fmaxf(s2 * (1.f / 192.f) - m * m, 0.f) + 1e-5f);
  } else {
    inB += (size_t)b * CHW;
    for (int g = tid; g < 128 * 192; g += 128) {
      int p = g / 192, c = g - p * 192;
      tile[p * 194 + c] = inB[(size_t)(p0 + p) * 192 + c];
    }
    __syncthreads();
    float s = 0.f, s2 = 0.f;
    for (int c = 0; c < 192; ++c) {
      float v = bf2f(tile[tid * 194 + c]);
      s += v; s2 += v * v;
    }
    float m = s * (1.f / 192.f);
    smu[tid] = m;
    srs[tid] = rsqrtf(fmaxf(s2 * (1.f / 192.f) - m * m, 0.f) + 1e-5f);
  }
  __syncthreads();
  for (int g = tid; g < 128 * 192; g += 128) {
    int p = g / 192, c = g - p * 192;
    float v = bf2f(tile[p * 194 + c]);
    float y = (v - smu[p]) * srs[p] * gw[c] + gb[c];
    out[(size_t)(p0 + p) * 192 + c] = f2bf(y);
  }
}

// ---------------------------------------------------------------------------
// Depthwise 3x3 SAME on transposed layout [b][HW][C].
// 8 channels x 4 consecutive w-pixels per thread; weights pre-transposed [9][C].
// ---------------------------------------------------------------------------
__global__ __launch_bounds__(256) void dwconv_kernel(
    const u16* __restrict__ in, const u16* __restrict__ wtT,
    u16* __restrict__ out, int C, int cg8)
{
  int idx = blockIdx.x * 256 + threadIdx.x;
  int cg   = idx % cg8;
  int rest = idx / cg8;
  int c  = cg << 3;
  int wg = rest & 31;
  int hb = rest >> 5;            // b*128 + h
  int h  = hb & 127;
  int w0 = wg << 2;

  float acc[4][8];
  #pragma unroll
  for (int px = 0; px < 4; ++px)
    #pragma unroll
    for (int j = 0; j < 8; ++j) acc[px][j] = 0.f;

  #pragma unroll
  for (int r = 0; r < 3; ++r) {
    int hh = h + r - 1;
    if (hh < 0 || hh > 127) continue;
    const u16* rowp = in + (size_t)(hb + r - 1) * 128 * C + c;
    bf16x8 v[6];
    #pragma unroll
    for (int t = 0; t < 6; ++t) {
      int ww = w0 + t - 1;
      if (ww < 0 || ww > 127) {
        #pragma unroll
        for (int j = 0; j < 8; ++j) v[t][j] = 0;
      } else {
        v[t] = *(const bf16x8*)(rowp + (size_t)ww * C);
      }
    }
    bf16x8 wv[3];
    #pragma unroll
    for (int kx = 0; kx < 3; ++kx)
      wv[kx] = *(const bf16x8*)(wtT + (size_t)(r * 3 + kx) * C + c);
    #pragma unroll
    for (int kx = 0; kx < 3; ++kx) {
      float wf[8];
      #pragma unroll
      for (int j = 0; j < 8; ++j) wf[j] = bf2f((u16)wv[kx][j]);
      #pragma unroll
      for (int px = 0; px < 4; ++px)
        #pragma unroll
        for (int j = 0; j < 8; ++j)
          acc[px][j] += bf2f((u16)v[px + kx][j]) * wf[j];
    }
  }

  #pragma unroll
  for (int px = 0; px < 4; ++px) {
    bf16x8 ov;
    #pragma unroll
    for (int j = 0; j < 8; ++j) ov[j] = (short)f2bf(acc[px][j]);
    *(bf16x8*)(out + (size_t)(hb * 128 + w0 + px) * C + c) = ov;
  }
}

// Sum of squares over pixels for q (ch 0..191) and k (ch 192..383) of QKVd.
__global__ __launch_bounds__(256) void norms_kernel(
    const u16* __restrict__ qkv, float* __restrict__ nrm)
{
  __shared__ float lacc[384];
  const int b = blockIdx.y, p0 = blockIdx.x * 128;
  for (int i = threadIdx.x; i < 384; i += 256) lacc[i] = 0.f;
  __syncthreads();
  const u16* base = qkv + (size_t)b * HWPIX * 576;
  for (int g = threadIdx.x; g < 128 * 48; g += 256) {
    int p = g / 48, cg = g - p * 48;
    bf16x8 v = *(const bf16x8*)(base + (size_t)(p0 + p) * 576 + cg * 8);
    #pragma unroll
    for (int j = 0; j < 8; ++j) {
      float x = bf2f((u16)v[j]);
      atomicAdd(&lacc[cg * 8 + j], x * x);
    }
  }
  __syncthreads();
  for (int i = threadIdx.x; i < 384; i += 256)
    atomicAdd(&nrm[b * 384 + i], lacc[i]);
}

// raw[b][h][c][d] += sum_p Q[p][h*32+c] * K[p][h*32+d]  (unnormalized dots)
__global__ __launch_bounds__(256) void qk_kernel(
    const u16* __restrict__ qkv, float* __restrict__ raw)
{
  __shared__ __align__(16) u16 Qt[64 * 32];
  __shared__ __align__(16) u16 Kt[64 * 32];
  const int b = blockIdx.z, h = blockIdx.y;
  const int tid = threadIdx.x;
  const u16* base = qkv + (size_t)b * HWPIX * 576;
  const int c = tid & 31, dg = tid >> 5;    // dg 0..7
  const int row = tid >> 2, colg = tid & 3;
  float a0 = 0.f, a1 = 0.f, a2 = 0.f, a3 = 0.f;
  const int pstart = blockIdx.x * 512;
  for (int p0 = pstart; p0 < pstart + 512; p0 += 64) {
    __syncthreads();
    const u16* qs = base + (size_t)(p0 + row) * 576 + h * 32 + colg * 8;
    *(bf16x8*)(Qt + row * 32 + colg * 8) = *(const bf16x8*)qs;
    *(bf16x8*)(Kt + row * 32 + colg * 8) = *(const bf16x8*)(qs + 192);
    __syncthreads();
    #pragma unroll 4
    for (int pp = 0; pp < 64; ++pp) {
      float qv = bf2f(Qt[pp * 32 + c]);
      a0 += qv * bf2f(Kt[pp * 32 + dg * 4 + 0]);
      a1 += qv * bf2f(Kt[pp * 32 + dg * 4 + 1]);
      a2 += qv * bf2f(Kt[pp * 32 + dg * 4 + 2]);
      a3 += qv * bf2f(Kt[pp * 32 + dg * 4 + 3]);
    }
  }
  float* dst = raw + (((size_t)(b * 6 + h) * 32 + c) * 32) + dg * 4;
  atomicAdd(dst + 0, a0);
  atomicAdd(dst + 1, a1);
  atomicAdd(dst + 2, a2);
  atomicAdd(dst + 3, a3);
}

// logits = raw * (1/max(|q|,eps)) * (1/max(|k|,eps)) * temp[h]; softmax over d(32)
__global__ __launch_bounds__(256) void softmax_kernel(
    float* __restrict__ raw, const float* __restrict__ nrm, const float* __restrict__ temp)
{
  int gid = blockIdx.x * 256 + threadIdx.x;   // 12288 total
  int d = gid & 31;
  int rowid = gid >> 5;
  int c = rowid & 31;
  int bh = rowid >> 5;
  int h = bh % 6, b = bh / 6;
  float sq = 1.f / fmaxf(sqrtf(nrm[b * 384 + h * 32 + c]), 1e-12f);
  float sk = 1.f / fmaxf(sqrtf(nrm[b * 384 + 192 + h * 32 + d]), 1e-12f);
  float logit = raw[gid] * sq * sk * temp[h];
  float m = logit;
  #pragma unroll
  for (int off = 16; off >= 1; off >>= 1)
    m = fmaxf(m, __shfl_xor(m, off, 32));
  float e = expf(logit - m);
  float s = e;
  #pragma unroll
  for (int off = 16; off >= 1; off >>= 1)
    s += __shfl_xor(s, off, 32);
  raw[gid] = e / s;
}

// out[p][h*32+cc] = sum_d attn[b][h][cc][d] * V[p][384+h*32+d]
__global__ __launch_bounds__(256) void attnout_kernel(
    const u16* __restrict__ qkv, const float* __restrict__ attn, u16* __restrict__ out)
{
  __shared__ float A[1024];
  const int b = blockIdx.z, h = blockIdx.y;
  const int p0 = blockIdx.x * 256;
  const float* am = attn + ((size_t)(b * 6 + h) * 32) * 32;
  for (int i = threadIdx.x; i < 1024; i += 256) A[i] = am[i];
  __syncthreads();
  const size_t pg = (size_t)b * HWPIX + p0 + threadIdx.x;
  const u16* vrow = qkv + pg * 576 + 384 + h * 32;
  float v[32];
  #pragma unroll
  for (int t = 0; t < 4; ++t) {
    bf16x8 vv = *(const bf16x8*)(vrow + t * 8);
    #pragma unroll
    for (int j = 0; j < 8; ++j) v[t * 8 + j] = bf2f((u16)vv[j]);
  }
  u16* orow = out + pg * 192 + h * 32;
  #pragma unroll
  for (int t = 0; t < 4; ++t) {
    bf16x8 ov;
    #pragma unroll
    for (int j = 0; j < 8; ++j) {
      const float* ar = &A[(t * 8 + j) * 32];
      float s = 0.f;
      #pragma unroll
      for (int d4 = 0; d4 < 8; ++d4) {
        f32x4 a4 = *(const f32x4*)(ar + d4 * 4);
        s += a4.x * v[d4 * 4 + 0] + a4.y * v[d4 * 4 + 1]
           + a4.z * v[d4 * 4 + 2] + a4.w * v[d4 * 4 + 3];
      }
      ov[j] = (short)f2bf(s);
    }
    *(bf16x8*)(orow + t * 8) = ov;
  }
}

__global__ void zero_kernel(float* p, int n) {
  int i = blockIdx.x * 256 + threadIdx.x;
  if (i < n) p[i] = 0.f;
}

// ---------------------------------------------------------------------------
extern "C" void kernel_launch(void* const* d_in, const int* in_sizes, int n_in,
                              void* d_out, int out_size, void* d_ws, size_t ws_size,
                              hipStream_t stream)
{
  (void)in_sizes; (void)n_in; (void)out_size; (void)ws_size;
  typedef const float* fp;
  fp x_in    = (fp)d_in[0];
  fp f_in    = (fp)d_in[1];
  fp nf_w    = (fp)d_in[2];
  fp nf_b    = (fp)d_in[3];
  fp n1_w    = (fp)d_in[4];
  fp n1_b    = (fp)d_in[5];
  fp n2_w    = (fp)d_in[6];
  fp n2_b    = (fp)d_in[7];
  fp a_cc_f  = (fp)d_in[8];
  fp a_fu_f  = (fp)d_in[9];
  fp a_mk_f  = (fp)d_in[10];
  fp a_qkv_f = (fp)d_in[11];
  fp a_dw_f  = (fp)d_in[12];
  fp a_temp  = (fp)d_in[13];
  fp a_pr_f  = (fp)d_in[14];
  fp f_pm_f  = (fp)d_in[15];
  fp f_pi_f  = (fp)d_in[16];
  fp f_dw_f  = (fp)d_in[17];
  fp f_cc_f  = (fp)d_in[18];
  fp f_fu_f  = (fp)d_in[19];
  fp f_mk_f  = (fp)d_in[20];
  fp f_po_f  = (fp)d_in[21];

  char* wsb = (char*)d_ws;
  const size_t U = 65536;   // bytes per channel-slab: 2 batches * 16384 px * 2B
  u16* Y     = (u16*)(wsb + (size_t)0    * U);  // [0,192)   residual, whole session
  u16* X1    = (u16*)(wsb + (size_t)192  * U);  // [192,384) until a_fu
  u16* MT    = (u16*)(wsb + (size_t)384  * U);  // [384,576) until a_cc
  float* nrm = (float*)(wsb + (size_t)576 * U); // slab 576 (52 KB) until attnout
  float* raw = nrm + 768;
  u16* QKV   = (u16*)(wsb + (size_t)640  * U);  // [640,1216) qkv gemm -> dwconv_a
  u16* OUT12 = (u16*)(wsb + (size_t)1344 * U);  // [1344,1728) a_cc -> a_fu
  u16* QKVd  = (u16*)(wsb + (size_t)1344 * U);  // [1344,1920) dwconv_a -> attnout
  u16* DW    = (u16*)(wsb + (size_t)1344 * U);  // [1344,2496) dwconv_f -> f_fu epi
  u16* FM    = (u16*)(wsb + (size_t)1920 * U);  // [1920,2496) f_pm -> f_mk
  u16* F     = (u16*)(wsb + (size_t)2496 * U);  // [2496,2688) ln_f -> a_mk
  u16* XD    = (u16*)(wsb + (size_t)2496 * U);  // a_fu -> qkv gemm
  u16* X2    = (u16*)(wsb + (size_t)2496 * U);  // ln2 -> f_pi
  u16* MT2   = (u16*)(wsb + (size_t)2496 * U);  // [2496,3072) f_mk -> f_cc epi
  u16* G     = (u16*)(wsb + (size_t)2496 * U);  // [2496,3072) f_fu epi5 -> final
  u16* AO    = (u16*)(wsb + (size_t)192  * U);  // attnout -> a_proj (X1 dead)
  u16* XIN   = (u16*)(wsb + (size_t)192  * U);  // [192,1344) f_pi -> dwconv_f
  u16* O12B  = (u16*)(wsb + (size_t)192  * U);  // f_cc -> f_fu
  // bf16 weight pool at [3072,...): rows padded to mult of 128
  u16* Wb    = (u16*)(wsb + (size_t)3072 * U);
  u16* a_cc_w  = Wb + 0;        // 384x384
  u16* a_fu_w  = Wb + 147456;   // 256x384 (O=192)
  u16* a_mk_w  = Wb + 245760;   // 256x192 (O=192)
  u16* a_qkv_w = Wb + 294912;   // 640x192 (O=576)
  u16* a_dw_w  = Wb + 417792;   // [9][576]
  u16* a_pr_w  = Wb + 422976;   // 256x192 (O=192)
  u16* f_pm_w  = Wb + 472128;   // 640x192 (O=576)
  u16* f_pi_w  = Wb + 595008;   // 1152x192
  u16* f_dw_w  = Wb + 816192;   // [9][1152]
  u16* f_cc_w  = Wb + 826560;   // 1152x1152
  u16* f_fu_w  = Wb + 2153664;  // 640x1152 (O=576)
  u16* f_mk_w  = Wb + 2890944;  // 640x576 (O=576)
  u16* f_po_w  = Wb + 3259584;  // 256x576 (O=192)

  CvtJobs jb;
  const float* srcs[15] = {a_cc_f, a_fu_f, a_mk_f, a_qkv_f, a_pr_f, f_pm_f,
                           f_pi_f, f_cc_f, f_fu_f, f_mk_f, f_po_f, a_dw_f, f_dw_f,
                           nullptr, nullptr};
  u16* dsts[15] = {a_cc_w, a_fu_w, a_mk_w, a_qkv_w, a_pr_w, f_pm_w,
                   f_pi_w, f_cc_w, f_fu_w, f_mk_w, f_po_w, a_dw_w, f_dw_w,
                   nullptr, nullptr};
  int Os[15]    = {384, 192, 192, 576, 192, 576, 1152, 1152, 576, 576, 192, 576, 1152, 0, 0};
  int Ks[15]    = {384, 384, 192, 192, 192, 192, 192, 1152, 1152, 576, 576, 0, 0, 8, 8};
  int Opads[15] = {384, 256, 256, 640, 256, 640, 1152, 1152, 640, 640, 256, 0, 0, 0, 0};
  int modes[15] = {0, 0, 0, 0, 0, 0, 0, 0, 0, 0, 0, 1, 1, 1, 1};
  for (int i = 0; i < 15; ++i) {
    jb.src[i] = srcs[i] ? srcs[i] : a_dw_f;
    jb.dst[i] = dsts[i] ? dsts[i] : a_dw_w;
    jb.O[i] = srcs[i] ? Os[i] : 8;
    jb.K[i] = Ks[i]; jb.Opad[i] = Opads[i]; jb.mode[i] = modes[i];
  }
  cvtall_kernel<<<dim3(648, 15), 256, 0, stream>>>(jb);

  dim3 lngrid(128, 2);
  zero_kernel<<<51, 256, 0, stream>>>(nrm, 13056);
  ln_kernel<<<lngrid, 128, 0, stream>>>(f_in, nullptr, 1, nf_w, nf_b, F);
  ln_kernel<<<lngrid, 128, 0, stream>>>(x_in, nullptr, 1, n1_w, n1_b, X1);

#define GEMM(W_, O_, OP_, K_, I1, S1, OF1, K1_, I2, S2, OF2, OUT_, SO_, EPI_, HALF_, E1_, SE1_, OFE1_, E2_, SE2_, OFE2_) \
  gemm_k<<<dim3(((OP_) / 128) * 256), 256, 0, stream>>>(W_, O_, K_, (OP_) / 128, I1, S1, OF1, K1_, I2, S2, OF2, OUT_, SO_, EPI_, HALF_, E1_, SE1_, OFE1_, E2_, SE2_, OFE2_)

  // FM = projmask @ F
  GEMM(f_pm_w, 576, 640, 192, F, 192, 0, 192, F, 192, 0, FM, 576, 0, 0, F, 192, 0, F, 192, 0);
  // MT = a_mask @ F
  GEMM(a_mk_w, 192, 256, 192, F, 192, 0, 192, F, 192, 0, MT, 192, 0, 0, F, 192, 0, F, 192, 0);
  // OUT12 = (a_concat @ [X1;MT] + 1) * [X1;MT]
  GEMM(a_cc_w, 384, 384, 384, X1, 192, 0, 192, MT, 192, 0, OUT12, 384, 1, 192, X1, 192, 0, MT, 192, 0);
  // XD = a_fusion @ OUT12 + X1
  GEMM(a_fu_w, 192, 256, 384, OUT12, 384, 0, 384, OUT12, 384, 0, XD, 192, 2, 0, X1, 192, 0, X1, 192, 0);
  // QKV = a_qkv @ XD
  GEMM(a_qkv_w, 576, 640, 192, XD, 192, 0, 192, XD, 192, 0, QKV, 576, 0, 0, XD, 192, 0, XD, 192, 0);
  dwconv_kernel<<<2304, 256, 0, stream>>>(QKV, a_dw_w, QKVd, 576, 72);
  norms_kernel<<<dim3(128, 2), 256, 0, stream>>>(QKVd, nrm);
  qk_kernel<<<dim3(32, 6, 2), 256, 0, stream>>>(QKVd, raw);
  softmax_kernel<<<48, 256, 0, stream>>>(raw, nrm, a_temp);
  attnout_kernel<<<dim3(64, 6, 2), 256, 0, stream>>>(QKVd, raw, AO);
  // Y = a_proj @ AO + x (natural fp32 residual)
  GEMM(a_pr_w, 192, 256, 192, AO, 192, 0, 192, AO, 192, 0, Y, 192, 3, 0, (const u16*)x_in, 0, 0, (const u16*)x_in, 0, 0);
  ln_kernel<<<lngrid, 128, 0, stream>>>(nullptr, Y, 0, n2_w, n2_b, X2);
  // XIN = projin @ X2
  GEMM(f_pi_w, 1152, 1152, 192, X2, 192, 0, 192, X2, 192, 0, XIN, 1152, 0, 0, X2, 192, 0, X2, 192, 0);
  // MT2 = f_mask @ FM   (after f_pi; before dwconv_f kills FM)
  GEMM(f_mk_w, 576, 640, 576, FM, 576, 0, 576, FM, 576, 0, MT2, 576, 0, 0, FM, 576, 0, FM, 576, 0);
  dwconv_kernel<<<4608, 256, 0, stream>>>(XIN, f_dw_w, DW, 1152, 144);
  // O12B = (f_concat @ [x2;MT2] + 1) * [x2;MT2]   (x2 = DW cols 576..1151)
  GEMM(f_cc_w, 1152, 1152, 1152, DW, 1152, 576, 576, MT2, 576, 0, O12B, 1152, 1, 576, DW, 1152, 576, MT2, 576, 0);
  // G = gelu(x1) * (f_fusion @ O12B + x2)   (fused epi 5, fast gelu)
  GEMM(f_fu_w, 576, 640, 1152, O12B, 1152, 0, 1152, O12B, 1152, 0, G, 576, 5, 0, DW, 1152, 576, DW, 1152, 576);
  // out = f_projout @ G + Y, stored natural fp32 [b][192][H][W]
  GEMM(f_po_w, 192, 256, 576, G, 576, 0, 576, G, 576, 0, (u16*)d_out, 192, 4, 0, Y, 192, 0, Y, 192, 0);
#undef GEMM
}